// Round 16
// baseline (729.704 us; speedup 1.0000x reference)
//
#include <hip/hip_runtime.h>
#include <hip/hip_bf16.h>

// ---------------------------------------------------------------------------
// CLUTRR transformer: B=64 S=512 H=256 L=4 NH=8 DH=32 F=1024 V=50265 K=8 R=25
// Round 16: attn grid (b fastest, qg, h) -> qg-sharers AND head-pairs of a
// batch on one XCD (K/V fetch sharing + full-line Ob write combining).
// poolcls: 1024 threads, 4-way split k-loop, mW2 staged. Rest = R15 (694 us).
// ---------------------------------------------------------------------------

typedef __hip_bfloat16 bf16;
typedef __attribute__((ext_vector_type(8))) short short8;
typedef __attribute__((ext_vector_type(4))) float f32x4;

#define S_LEN 512
#define H_DIM 256
#define NTOK  32768      // B*S
#define QSCALE 0.25503488f   // (1/sqrt(32)) * log2(e)

__device__ __forceinline__ void gload_lds16(const void* g, void* l) {
  __builtin_amdgcn_global_load_lds(
      (const __attribute__((address_space(1))) unsigned int*)g,
      (__attribute__((address_space(3))) unsigned int*)l, 16, 0, 0);
}

__device__ __forceinline__ unsigned short f2bu(float x) {
  bf16 t = __float2bfloat16(x);
  return *reinterpret_cast<unsigned short*>(&t);
}
__device__ __forceinline__ float bu2f(unsigned short u) {
  unsigned int x = (unsigned int)u << 16;
  return __uint_as_float(x);
}

// -------- per-batch: exact valid length + tile count --------
__global__ __launch_bounds__(64) void lens_kernel(
    const int* __restrict__ amask, int* __restrict__ ntiles,
    int* __restrict__ lenb) {
  const int b = blockIdx.x, t = threadIdx.x;
  int c = 0;
#pragma unroll
  for (int i = 0; i < 8; ++i) c += amask[b * S_LEN + t + i * 64];
#pragma unroll
  for (int off = 1; off < 64; off <<= 1) c += __shfl_xor(c, off);
  if (t == 0) {
    lenb[b] = c;
    ntiles[b] = (c + 63) >> 6;
  }
}

// -------- rank-sort batches by tile count (descending) --------
__global__ __launch_bounds__(64) void order_kernel(
    const int* __restrict__ ntiles, int* __restrict__ ordb) {
  const int b = threadIdx.x;
  const int ntb = ntiles[b];
  int rank = 0;
  for (int j = 0; j < 64; ++j) {
    const int ntj = __shfl(ntb, j);
    rank += (ntj > ntb) || (ntj == ntb && j < b);
  }
  ordb[rank] = b;
}

// -------- weight cast + transpose: out[N][K] = bf16(in[K][N]) --------
__global__ __launch_bounds__(256) void tcast_kernel(
    const float* __restrict__ in, bf16* __restrict__ out, int K, int N) {
  const int l = blockIdx.z;
  in  += (size_t)l * K * N;
  out += (size_t)l * K * N;
  __shared__ float t[32][33];
  const int n0 = blockIdx.x * 32, k0 = blockIdx.y * 32;
  const int c = threadIdx.x & 31, r = threadIdx.x >> 5;
#pragma unroll
  for (int rr = r; rr < 32; rr += 8)
    t[rr][c] = in[(size_t)(k0 + rr) * N + n0 + c];
  __syncthreads();
#pragma unroll
  for (int rr = r; rr < 32; rr += 8)
    out[(size_t)(n0 + rr) * K + k0 + c] = __float2bfloat16(t[c][rr]);
}

// -------- embedding gather: Xb bf16 only --------
__global__ __launch_bounds__(256) void embed_kernel(
    const int* __restrict__ ids, const float* __restrict__ emb,
    bf16* __restrict__ Xb) {
  size_t i4 = (size_t)blockIdx.x * 256 + threadIdx.x;   // float4 index
  int tok = (int)(i4 >> 6);
  int d4  = (int)(i4 & 63);
  float4 v = *(const float4*)&emb[(size_t)ids[tok] * H_DIM + d4 * 4];
  ushort4 pk;
  pk.x = f2bu(v.x); pk.y = f2bu(v.y); pk.z = f2bu(v.z); pk.w = f2bu(v.w);
  *(ushort4*)&Xb[i4 * 4] = pk;
}

// Staging-source chunk swizzle: lane tid stages 8 elems; LDS pos (tid&3),
// global chunk (tid&3)^((tid>>3)&3). Read side: chunk = g4 ^ ((fr>>1)&3).
#define SRC_CHUNK(tid_) (((tid_) & 3) ^ (((tid_) >> 3) & 3))

// -------- bf16 MFMA GEMM, 2-phase dbuf + LDS-coalesced epilogue --------
// Grid: x = m-tile (fastest -> same-XCD A-panel sharing), y = n-tile.
// MODE 1: bf16 out Cb (w/ optional relu);
// MODE 2: QKV split — n<256 -> Q prescaled; <512 -> K; >=512 -> Vt swizzled.
template<int MODE, bool RELU>
__global__ __launch_bounds__(256) void hgemm_kernel(
    const bf16* __restrict__ A, const bf16* __restrict__ Bt,
    const float* __restrict__ bias, float* __restrict__ Cf,
    bf16* __restrict__ Cb, bf16* __restrict__ Vt,
    int M, int N, int K) {
  // 32KB shared: K-loop staging [2][As 4096 | Bs 4096]; epilogue 128x128 tile
  __shared__ __align__(16) bf16 Sh[16384];
  bf16* const As0 = Sh;          // [2][4096]
  bf16* const Bs0 = Sh + 8192;   // [2][4096]
  const int tid = threadIdx.x;
  const int wv = tid >> 6, ln = tid & 63;
  const int fr = ln & 15, g4 = ln >> 4;
  const int wr = wv >> 1, wc = wv & 1;
  const int m0 = blockIdx.x * 128, n0 = blockIdx.y * 128;
  const int lr = tid >> 2;                     // staging row
  const int lk = SRC_CHUNK(tid) * 8;           // swizzled source k-offset
  const int rc = (g4 ^ ((fr >> 1) & 3)) * 8;   // swizzled read chunk (elems)

#define STAGE_G(buf, kk) do {                                                  \
    const int kof_ = (kk) * 32;                                                \
    gload_lds16(A  + (size_t)(m0 + lr) * K + kof_ + lk,                        \
                &As0[(buf) * 4096 + wv * 512]);                                \
    gload_lds16(A  + (size_t)(m0 + 64 + lr) * K + kof_ + lk,                   \
                &As0[(buf) * 4096 + 2048 + wv * 512]);                         \
    gload_lds16(Bt + (size_t)(n0 + lr) * K + kof_ + lk,                        \
                &Bs0[(buf) * 4096 + wv * 512]);                                \
    gload_lds16(Bt + (size_t)(n0 + 64 + lr) * K + kof_ + lk,                   \
                &Bs0[(buf) * 4096 + 2048 + wv * 512]);                         \
  } while (0)

  f32x4 acc[4][4];
#pragma unroll
  for (int i = 0; i < 4; ++i)
#pragma unroll
    for (int j = 0; j < 4; ++j)
      acc[i][j] = (f32x4){0.f, 0.f, 0.f, 0.f};

  const int NT = K >> 5;
  STAGE_G(0, 0);
  __syncthreads();
  int cur = 0;
  for (int kt = 0; kt < NT; ++kt) {
    if (kt + 1 < NT) STAGE_G(cur ^ 1, kt + 1);
    short8 af[4], bfv[4];
#pragma unroll
    for (int i = 0; i < 4; ++i)
      af[i] = *(const short8*)
          &As0[cur * 4096 + (wr * 64 + i * 16 + fr) * 32 + rc];
#pragma unroll
    for (int j = 0; j < 4; ++j)
      bfv[j] = *(const short8*)
          &Bs0[cur * 4096 + (wc * 64 + j * 16 + fr) * 32 + rc];
#pragma unroll
    for (int i = 0; i < 4; ++i)
#pragma unroll
      for (int j = 0; j < 4; ++j)
        acc[i][j] = __builtin_amdgcn_mfma_f32_16x16x32_bf16(
            af[i], bfv[j], acc[i][j], 0, 0, 0);
    __syncthreads();
    cur ^= 1;
  }
#undef STAGE_G

  // ---- epilogue: stage C tile in LDS (chunk-XOR swizzled), store coalesced
  const bool vpath = (MODE == 2) && (n0 >= 512);
#pragma unroll
  for (int j = 0; j < 4; ++j) {
    const int nl = wc * 64 + j * 16 + fr;
    const int n = n0 + nl;
    const float bv = bias[n];
    const float sc = (MODE == 2 && n < 256) ? QSCALE : 1.0f;
#pragma unroll
    for (int i = 0; i < 4; ++i) {
      const int mlb = wr * 64 + i * 16 + g4 * 4;
#pragma unroll
      for (int r = 0; r < 4; ++r) {
        float o = acc[i][j][r] + bv;
        if (RELU) o = fmaxf(o, 0.f);
        o *= sc;
        const int ml = mlb + r;
        const int addr = vpath ? nl * 128 + (ml ^ ((nl & 7) << 3))
                               : ml * 128 + (nl ^ ((ml & 7) << 3));
        Sh[addr] = __float2bfloat16(o);
      }
    }
  }
  __syncthreads();
  if (!vpath) {
    const int ldc = (MODE == 1) ? N : 768;
#pragma unroll
    for (int p = 0; p < 8; ++p) {
      const int cid = p * 256 + tid;
      const int ml = cid >> 4, mc = cid & 15;
      const short8 v =
          *(const short8*)&Sh[ml * 128 + ((mc * 8) ^ ((ml & 7) << 3))];
      *(short8*)&Cb[(size_t)(m0 + ml) * ldc + n0 + mc * 8] = v;
    }
  } else {
    const int bb = m0 >> 9;
#pragma unroll
    for (int p = 0; p < 8; ++p) {
      const int cid = p * 256 + tid;
      const int ddl = cid >> 4, mc = cid & 15;
      const short8 v =
          *(const short8*)&Sh[ddl * 128 + ((mc * 8) ^ ((ddl & 7) << 3))];
      const int dd = (n0 - 512) + ddl;
      const int hh = dd >> 5, ddd = dd & 31;
      const int s8 = (m0 & 511) + mc * 8;
      const int ssw = (s8 & ~63) | ((s8 & 63) ^ ((ddd & 7) << 3));
      *(short8*)&Vt[(((size_t)bb * 8 + hh) * 32 + ddd) * 512 + ssw] = v;
    }
  }
}

// -------- fused GEMM + bias + residual(bf16) + LayerNorm -> Xb bf16 --------
__global__ __launch_bounds__(256) void hgemm_ln_kernel(
    const bf16* __restrict__ A, const bf16* __restrict__ Bt,
    const float* __restrict__ bias, bf16* __restrict__ Xbf,
    const float* __restrict__ g, const float* __restrict__ bt, int K) {
  __shared__ __align__(16) bf16 Sh[20480];     // 40KB
  bf16* const As0 = Sh;                        // [2][2048] (8KB)
  bf16* const Bs0 = Sh + 4096;                 // [2][8192] (32KB)
  // epilogue aliases (staging dead after K-loop):
  float* const rsum = (float*)Sh;              // 256 floats (1KB)
  float* const rsq  = (float*)(Sh + 512);      // 256 floats (1KB)
  bf16*  const XbT  = Sh + 1024;               // [64][256] bf16 (32KB)
  const int tid = threadIdx.x;
  const int wv = tid >> 6;
  const int ln = tid & 63;
  const int fr = ln & 15, g4 = ln >> 4;
  const int m0 = blockIdx.x * 64;
  const int rc = (g4 ^ ((fr >> 1) & 3)) * 8;

#define STAGE_L(buf, kk) do {                                                  \
    const int kof_ = (kk) * 32;                                                \
    gload_lds16(A + (size_t)(m0 + (tid >> 2)) * K + kof_ +                     \
                    SRC_CHUNK(tid) * 8,                                        \
                &As0[(buf) * 2048 + wv * 512]);                                \
    _Pragma("unroll")                                                          \
    for (int e = 0; e < 4; ++e) {                                              \
      const int vt = e * 256 + tid;                                            \
      gload_lds16(Bt + (size_t)(vt >> 2) * K + kof_ + SRC_CHUNK(vt) * 8,       \
                  &Bs0[(buf) * 8192 + e * 2048 + wv * 512]);                   \
    }                                                                          \
  } while (0)

  f32x4 acc[4][4];   // [row frag i][col frag j]
#pragma unroll
  for (int i = 0; i < 4; ++i)
#pragma unroll
    for (int j = 0; j < 4; ++j)
      acc[i][j] = (f32x4){0.f, 0.f, 0.f, 0.f};

  const int NT = K >> 5;
  STAGE_L(0, 0);
  __syncthreads();
  int cur = 0;
  for (int kt = 0; kt < NT; ++kt) {
    if (kt + 1 < NT) STAGE_L(cur ^ 1, kt + 1);
    short8 af[4], bfv[4];
#pragma unroll
    for (int i = 0; i < 4; ++i)
      af[i] = *(const short8*)&As0[cur * 2048 + (i * 16 + fr) * 32 + rc];
#pragma unroll
    for (int j = 0; j < 4; ++j)
      bfv[j] = *(const short8*)
          &Bs0[cur * 8192 + (wv * 64 + j * 16 + fr) * 32 + rc];
#pragma unroll
    for (int i = 0; i < 4; ++i)
#pragma unroll
      for (int j = 0; j < 4; ++j)
        acc[i][j] = __builtin_amdgcn_mfma_f32_16x16x32_bf16(
            af[i], bfv[j], acc[i][j], 0, 0, 0);
    __syncthreads();
    cur ^= 1;
  }
#undef STAGE_L

  // ---- stage residual tile Xbf[m0..m0+63][0..255] into XbT (linear) ----
#pragma unroll
  for (int p = 0; p < 8; ++p) {
    const int seg = p * 4 + wv;   // 32 segments x 512 elems (2 rows each)
    gload_lds16(Xbf + (size_t)(m0 + seg * 2 + (ln >> 5)) * 256 +
                    (ln & 31) * 8,
                &XbT[seg * 512]);
  }
  __syncthreads();

  // ---- bias + residual ----
  float gj[4], bj[4], bsj[4];
#pragma unroll
  for (int j = 0; j < 4; ++j) {
    const int n = wv * 64 + j * 16 + fr;
    gj[j] = g[n]; bj[j] = bt[n]; bsj[j] = bias[n];
  }
#pragma unroll
  for (int i = 0; i < 4; ++i) {
#pragma unroll
    for (int r = 0; r < 4; ++r) {
      const int ml = i * 16 + g4 * 4 + r;
#pragma unroll
      for (int j = 0; j < 4; ++j) {
        const int nl = wv * 64 + j * 16 + fr;
        acc[i][j][r] += bsj[j] +
            bu2f(*(const unsigned short*)&XbT[ml * 256 + nl]);
      }
    }
  }
  // ---- LN stats ----
#pragma unroll
  for (int i = 0; i < 4; ++i) {
#pragma unroll
    for (int r = 0; r < 4; ++r) {
      float sp = acc[i][0][r] + acc[i][1][r] + acc[i][2][r] + acc[i][3][r];
      float qp = acc[i][0][r] * acc[i][0][r] + acc[i][1][r] * acc[i][1][r] +
                 acc[i][2][r] * acc[i][2][r] + acc[i][3][r] * acc[i][3][r];
#pragma unroll
      for (int off = 1; off < 16; off <<= 1) {
        sp += __shfl_xor(sp, off);
        qp += __shfl_xor(qp, off);
      }
      if (fr == 0) {
        const int ri = i * 16 + g4 * 4 + r;
        rsum[wv * 64 + ri] = sp;
        rsq[wv * 64 + ri] = qp;
      }
    }
  }
  __syncthreads();
  // ---- normalize + write swizzled bf16 tile ----
#pragma unroll
  for (int i = 0; i < 4; ++i) {
#pragma unroll
    for (int r = 0; r < 4; ++r) {
      const int ri = i * 16 + g4 * 4 + r;
      const float tot = rsum[ri] + rsum[64 + ri] + rsum[128 + ri] +
                        rsum[192 + ri];
      const float tq = rsq[ri] + rsq[64 + ri] + rsq[128 + ri] + rsq[192 + ri];
      const float mu = tot * (1.0f / 256.0f);
      const float var = tq * (1.0f / 256.0f) - mu * mu;
      const float rstd = rsqrtf(var + 1e-5f);
#pragma unroll
      for (int j = 0; j < 4; ++j) {
        const int nl = wv * 64 + j * 16 + fr;
        const float o = (acc[i][j][r] - mu) * rstd * gj[j] + bj[j];
        XbT[ri * 256 + (nl ^ ((ri & 7) << 3))] = __float2bfloat16(o);
      }
    }
  }
  __syncthreads();
#pragma unroll
  for (int p = 0; p < 8; ++p) {
    const int c8 = p * 256 + tid;
    const int row = c8 >> 5, cc = c8 & 31;
    const short8 v =
        *(const short8*)&XbT[row * 256 + ((cc * 8) ^ ((row & 7) << 3))];
    *(short8*)&Xbf[(size_t)(m0 + row) * 256 + cc * 8] = v;
  }
}

// -------- bf16 MFMA flash attention: 512 threads, 8 waves, 128 q-rows ------
// Grid (b fastest, qg, h): all 32 blocks of a batch (4 qg x 8 h) share one
// XCD (qg stride 64, h stride 256, both = 0 mod 8) -> K/V L2 sharing AND
// full-line Ob write combining across head pairs.
__global__ __launch_bounds__(512, 8) void attn_mfma_kernel(
    const bf16* __restrict__ QKVb, const bf16* __restrict__ Vt,
    const int* __restrict__ amask, const int* __restrict__ ntiles,
    const int* __restrict__ ordb, bf16* __restrict__ Ob) {
  const int b = ordb[blockIdx.x];
  const int qg = blockIdx.y;         // 0..3 -> q rows qg*128..+127
  const int h = blockIdx.z;
  const int tid = threadIdx.x;       // 0..511
  const int wv = tid >> 6, ln = tid & 63;
  const int fr = ln & 15, g4 = ln >> 4;
  const int f8 = (fr & 7) << 3;
  const int rc = (g4 ^ ((fr >> 1) & 3)) * 8;   // swizzled K/Q read chunk
  const int bh32 = (b * 8 + h) * 32;
  __shared__ __align__(16) bf16 Ks[2][2048];   // [buf][64][32], chunk-swz
  __shared__ __align__(16) bf16 Vs[2][2048];   // [buf][32 d][64 k] swizzled
  __shared__ __align__(16) bf16 Ps[8192];      // Q staging (128x32); then
                                               // 8 per-wave P tiles [16][64]
  __shared__ __align__(16) float Ms[64];

  const int nt = ntiles[b];

#define STAGE_A(buf, kt_) do {                                                 \
    if (tid < 256) {                                                           \
      const int k0_ = (kt_) * 64;                                              \
      gload_lds16(QKVb + (size_t)(b * S_LEN + k0_ + (tid >> 2)) * 768 + 256 +  \
                      h * 32 + SRC_CHUNK(tid) * 8,                             \
                  &Ks[(buf)][wv * 512]);                                       \
      gload_lds16(Vt + (size_t)(bh32 + (tid >> 3)) * 512 + k0_ +               \
                      (tid & 7) * 8,                                           \
                  &Vs[(buf)][wv * 512]);                                       \
      if ((kt_) == nt - 1 && tid < 64)                                         \
        Ms[tid] = (amask[b * S_LEN + k0_ + tid] != 0) ? 0.f : -1e9f;           \
    }                                                                          \
  } while (0)

  // stage 128 Q rows into Ps[0..4095] (wave w -> rows w*16..+15)
  gload_lds16(QKVb + (size_t)(b * S_LEN + qg * 128 + (tid >> 2)) * 768 +
                  h * 32 + SRC_CHUNK(tid) * 8,
              &Ps[wv * 512]);
  STAGE_A(0, 0);
  __syncthreads();
  const short8 qb = *(const short8*)&Ps[wv * 512 + fr * 32 + rc];
  __syncthreads();   // all Q-frag reads done before any P write

  f32x4 accO[2];
  accO[0] = (f32x4){0.f, 0.f, 0.f, 0.f};
  accO[1] = (f32x4){0.f, 0.f, 0.f, 0.f};
  float mrun = -1e30f, lrun = 0.f;   // per-lane state for q = fr (log2 domain)
  const int srcq = 20 * g4;   // shfl src base: lane 16*g4 + (4*g4 + rr)

  int cur = 0;
  for (int kt = 0; kt < nt; ++kt) {
    if (kt + 1 < nt) STAGE_A(cur ^ 1, kt + 1);
    const bool bnd = (kt == nt - 1);

    // S^T = K @ Q^T : 4 MFMAs cover 64 k x 16 q (already log2-scaled via Q)
    f32x4 st[4];
#pragma unroll
    for (int kb = 0; kb < 4; ++kb) {
      const short8 kf = *(const short8*)&Ks[cur][(kb * 16 + fr) * 32 + rc];
      f32x4 z = (f32x4){0.f, 0.f, 0.f, 0.f};
      st[kb] = __builtin_amdgcn_mfma_f32_16x16x32_bf16(kf, qb, z, 0, 0, 0);
    }

    float p[16];
    if (bnd) {
#pragma unroll
      for (int kb = 0; kb < 4; ++kb) {
        const f32x4 mv = ((const f32x4*)Ms)[kb * 4 + g4];
#pragma unroll
        for (int rr = 0; rr < 4; ++rr) p[kb * 4 + rr] = st[kb][rr] + mv[rr];
      }
    } else {
#pragma unroll
      for (int kb = 0; kb < 4; ++kb)
#pragma unroll
        for (int rr = 0; rr < 4; ++rr) p[kb * 4 + rr] = st[kb][rr];
    }

    // max: v_max3 tree (depth 3) + 2 cross-lane
    const float a0 = fmaxf(fmaxf(p[0], p[1]), p[2]);
    const float a1 = fmaxf(fmaxf(p[3], p[4]), p[5]);
    const float a2 = fmaxf(fmaxf(p[6], p[7]), p[8]);
    const float a3 = fmaxf(fmaxf(p[9], p[10]), p[11]);
    const float a4 = fmaxf(fmaxf(p[12], p[13]), p[14]);
    float mx = fmaxf(fmaxf(fmaxf(a0, a1), fmaxf(a2, a3)), fmaxf(a4, p[15]));
    mx = fmaxf(mx, __shfl_xor(mx, 16));
    mx = fmaxf(mx, __shfl_xor(mx, 32));

    // defer-max (T13): rescale only when the row max grew by > 8 (log2)
    float corr = 1.f;
    if (!__all(mx <= mrun + 8.f)) {
      const float mnew = fmaxf(mrun, mx);
      corr = exp2f(mrun - mnew);
      mrun = mnew;
#pragma unroll
      for (int rr = 0; rr < 4; ++rr) {
        const float cs = __shfl(corr, srcq + rr);
        accO[0][rr] *= cs;
        accO[1][rr] *= cs;
      }
    }

#pragma unroll
    for (int i = 0; i < 16; ++i) p[i] = exp2f(p[i] - mrun);
    // pairwise-tree sum (depth 4) + 2 cross-lane
    const float b0 = p[0] + p[1], b1 = p[2] + p[3], b2 = p[4] + p[5],
                b3 = p[6] + p[7], b4 = p[8] + p[9], b5 = p[10] + p[11],
                b6 = p[12] + p[13], b7 = p[14] + p[15];
    float ps = ((b0 + b1) + (b2 + b3)) + ((b4 + b5) + (b6 + b7));
    ps += __shfl_xor(ps, 16);
    ps += __shfl_xor(ps, 32);
    lrun = lrun * corr + ps;

    // write P rows: lane writes 4 shorts per kb at k = kb*16 + g4*4, XOR-swz
#pragma unroll
    for (int kb = 0; kb < 4; ++kb) {
      ushort4 w4;
      w4.x = f2bu(p[kb * 4 + 0]);
      w4.y = f2bu(p[kb * 4 + 1]);
      w4.z = f2bu(p[kb * 4 + 2]);
      w4.w = f2bu(p[kb * 4 + 3]);
      *(ushort4*)&Ps[wv * 1024 + fr * 64 + ((kb * 16 + g4 * 4) ^ f8)] = w4;
    }

    // PV: O[q][d] += P[16q x 32k] @ V[32k x 16d], per-wave (no barrier)
#pragma unroll
    for (int kk = 0; kk < 2; ++kk) {
      const short8 pa = *(const short8*)
          &Ps[wv * 1024 + fr * 64 + ((kk * 32 + g4 * 8) ^ f8)];
#pragma unroll
      for (int df = 0; df < 2; ++df) {
        const short8 vb = *(const short8*)
            &Vs[cur][(df * 16 + fr) * 64 + ((kk * 32 + g4 * 8) ^ f8)];
        accO[df] = __builtin_amdgcn_mfma_f32_16x16x32_bf16(
            pa, vb, accO[df], 0, 0, 0);
      }
    }
    __syncthreads();
    cur ^= 1;
  }
#undef STAGE_A

  const float inv = 1.0f / lrun;   // q = fr layout
#pragma unroll
  for (int rr = 0; rr < 4; ++rr) {
    const float iv = __shfl(inv, srcq + rr);
    const int q = qg * 128 + wv * 16 + g4 * 4 + rr;
    const size_t orow = ((size_t)b * S_LEN + q) * H_DIM + h * 32;
    Ob[orow + fr]      = __float2bfloat16(accO[0][rr] * iv);
    Ob[orow + 16 + fr] = __float2bfloat16(accO[1][rr] * iv);
  }
}

// -------- fused final-LN + story-pool stage1 (bf16 stream) --------
__global__ __launch_bounds__(256) void lnf_pool_kernel(
    bf16* __restrict__ Xbf, const float* __restrict__ g,
    const float* __restrict__ bt, const int* __restrict__ amask,
    float* __restrict__ Pstory) {
  const int b = blockIdx.x, sg = blockIdx.y;
  const int tid = threadIdx.x, wv = tid >> 6, ln = tid & 63;
  const float4 gg = ((const float4*)g)[ln];
  const float4 bb = ((const float4*)bt)[ln];
  float ax = 0.f, ay = 0.f, az = 0.f, aw = 0.f;
  for (int t = wv; t < 64; t += 4) {
    const size_t tok = (size_t)b * S_LEN + sg * 64 + t;
    const ushort4 u = *(const ushort4*)&Xbf[tok * 256 + ln * 4];
    const float vx = bu2f(u.x), vy = bu2f(u.y), vz = bu2f(u.z),
                vw = bu2f(u.w);
    float s = vx + vy + vz + vw;
#pragma unroll
    for (int off = 1; off < 64; off <<= 1) s += __shfl_xor(s, off);
    const float mu = s * (1.0f / 256.0f);
    const float dx = vx - mu, dy = vy - mu, dz = vz - mu, dw = vw - mu;
    float sq = dx * dx + dy * dy + dz * dz + dw * dw;
#pragma unroll
    for (int off = 1; off < 64; off <<= 1) sq += __shfl_xor(sq, off);
    const float rstd = rsqrtf(sq * (1.0f / 256.0f) + 1e-5f);
    const float ox = dx * rstd * gg.x + bb.x;
    const float oy = dy * rstd * gg.y + bb.y;
    const float oz = dz * rstd * gg.z + bb.z;
    const float ow = dw * rstd * gg.w + bb.w;
    ushort4 o4;
    o4.x = f2bu(ox); o4.y = f2bu(oy); o4.z = f2bu(oz); o4.w = f2bu(ow);
    *(ushort4*)&Xbf[tok * 256 + ln * 4] = o4;
    if (amask[tok]) { ax += ox; ay += oy; az += oz; aw += ow; }
  }
  __shared__ float part[4][256];
  part[wv][ln * 4 + 0] = ax;
  part[wv][ln * 4 + 1] = ay;
  part[wv][ln * 4 + 2] = az;
  part[wv][ln * 4 + 3] = aw;
  __syncthreads();
  const float tot = part[0][tid] + part[1][tid] + part[2][tid] + part[3][tid];
  Pstory[((size_t)b * 8 + sg) * 256 + tid] = tot;
}

// -------- pool combine + classifier: 1024 threads, split k-loop --------
__global__ __launch_bounds__(1024) void poolcls_kernel(
    const bf16* __restrict__ Xbf, const float* __restrict__ Pstory,
    const int* __restrict__ lenb,
    const int* __restrict__ sub_idx, const int* __restrict__ sub_cnt,
    const int* __restrict__ obj_idx, const int* __restrict__ obj_cnt,
    const float* __restrict__ mW1, const float* __restrict__ mb1,
    const float* __restrict__ mW2, const float* __restrict__ mb2,
    float* __restrict__ out) {
  const int b = blockIdx.x, tid = threadIdx.x;
  const int t = tid & 255, sl = tid >> 8;   // channel, slice 0-3
  __shared__ float fs[768];
  __shared__ float part[4][256];
  __shared__ float hid[256];
  __shared__ float w2s[256 * 25];
  const bf16* xb = Xbf + (size_t)b * S_LEN * H_DIM;
  // stage mW2 (25.6KB) while computing fs
  for (int i = tid; i < 6400; i += 1024) w2s[i] = mW2[i];
  if (sl == 0) {
    float s = 0.f;
#pragma unroll
    for (int i = 0; i < 8; ++i) s += Pstory[((size_t)b * 8 + i) * 256 + t];
    fs[512 + t] = s / (float)lenb[b];   // len >= 16
  } else if (sl == 1) {
    const int cc = sub_cnt[b];
    float s2 = 0.f;
    for (int j = 0; j < cc; ++j)
      s2 += __bfloat162float(xb[(size_t)sub_idx[b * 8 + j] * H_DIM + t]);
    fs[t] = (cc > 0) ? s2 / (float)cc : 0.f;
  } else if (sl == 2) {
    const int cc = obj_cnt[b];
    float s2 = 0.f;
    for (int j = 0; j < cc; ++j)
      s2 += __bfloat162float(xb[(size_t)obj_idx[b * 8 + j] * H_DIM + t]);
    fs[256 + t] = (cc > 0) ? s2 / (float)cc : 0.f;
  }
  __syncthreads();
  // hidden GEMM: slice sl covers k in [sl*192, sl*192+192)
  float acc = 0.f;
  for (int k = sl * 192; k < sl * 192 + 192; ++k)
    acc += fs[k] * mW1[(size_t)k * 256 + t];
  part[sl][t] = acc;
  __syncthreads();
  if (sl == 0)
    hid[t] = fmaxf(part[0][t] + part[1][t] + part[2][t] + part[3][t] +
                       mb1[t],
                   0.f);
  __syncthreads();
  if (tid < 25) {
    float o = mb2[tid];
    for (int j = 0; j < 256; ++j) o += hid[j] * w2s[j * 25 + tid];
    out[b * 25 + tid] = o;
  }
}

// ---------------------------------------------------------------------------
extern "C" void kernel_launch(void* const* d_in, const int* in_sizes, int n_in,
                              void* d_out, int out_size, void* d_ws, size_t ws_size,
                              hipStream_t stream) {
  const int*   input_ids = (const int*)d_in[0];
  const int*   amask     = (const int*)d_in[1];
  const int*   sub_idx   = (const int*)d_in[2];
  const int*   sub_cnt   = (const int*)d_in[3];
  const int*   obj_idx   = (const int*)d_in[4];
  const int*   obj_cnt   = (const int*)d_in[5];
  const float* emb  = (const float*)d_in[6];
  const float* Wqkv = (const float*)d_in[7];
  const float* bqkv = (const float*)d_in[8];
  const float* Wo   = (const float*)d_in[9];
  const float* bo   = (const float*)d_in[10];
  const float* ln1g = (const float*)d_in[11];
  const float* ln1b = (const float*)d_in[12];
  const float* ln2g = (const float*)d_in[13];
  const float* ln2b = (const float*)d_in[14];
  const float* W1   = (const float*)d_in[15];
  const float* b1   = (const float*)d_in[16];
  const float* W2   = (const float*)d_in[17];
  const float* b2   = (const float*)d_in[18];
  const float* lnfg = (const float*)d_in[19];
  const float* lnfb = (const float*)d_in[20];
  const float* mW1  = (const float*)d_in[21];
  const float* mb1  = (const float*)d_in[22];
  const float* mW2  = (const float*)d_in[23];
  const float* mb2  = (const float*)d_in[24];
  float* out = (float*)d_out;

  // workspace layout (bytes)
  char* w = (char*)d_ws;
  bf16*  Xb   = (bf16*)w;                          w += (size_t)NTOK * 256 * 2;  // 16.8MB
  bf16*  QKVb = (bf16*)w;                          w += (size_t)NTOK * 768 * 2;  // 50.3MB
  bf16*  Vtg  = (bf16*)w;                          w += (size_t)NTOK * 256 * 2;  // 16.8MB
  bf16*  Ob   = (bf16*)w;                          w += (size_t)NTOK * 256 * 2;  // 16.8MB
  bf16*  Wqkvt= (bf16*)w;                          w += (size_t)4 * 768 * 256 * 2;
  bf16*  Wot  = (bf16*)w;                          w += (size_t)4 * 256 * 256 * 2;
  bf16*  W1t  = (bf16*)w;                          w += (size_t)4 * 1024 * 256 * 2;
  bf16*  W2t  = (bf16*)w;                          w += (size_t)4 * 256 * 1024 * 2;
  float* Pstory = (float*)w;                       w += (size_t)64 * 8 * 256 * 4;
  int*   ntiles = (int*)w;                         w += 256;
  int*   lenb   = (int*)w;                         w += 256;
  int*   ordb   = (int*)w;                         w += 256;
  bf16*  Hb   = QKVb;   // aliases [QKVb, Vtg] = 67.1MB >= 32768*1024*2

  lens_kernel<<<64, 64, 0, stream>>>(amask, ntiles, lenb);
  order_kernel<<<1, 64, 0, stream>>>(ntiles, ordb);
  tcast_kernel<<<dim3(24, 8, 4), 256, 0, stream>>>(Wqkv, Wqkvt, 256, 768);
  tcast_kernel<<<dim3(8, 8, 4), 256, 0, stream>>>(Wo, Wot, 256, 256);
  tcast_kernel<<<dim3(32, 8, 4), 256, 0, stream>>>(W1, W1t, 256, 1024);
  tcast_kernel<<<dim3(8, 32, 4), 256, 0, stream>>>(W2, W2t, 1024, 256);

  embed_kernel<<<8192, 256, 0, stream>>>(input_ids, emb, Xb);

  for (int l = 0; l < 4; ++l) {
    const bf16* Wqkvt_l = Wqkvt + (size_t)l * 768 * 256;
    const bf16* Wot_l   = Wot + (size_t)l * 256 * 256;
    const bf16* W1t_l   = W1t + (size_t)l * 1024 * 256;
    const bf16* W2t_l   = W2t + (size_t)l * 256 * 1024;

    hgemm_kernel<2, false><<<dim3(256, 6), 256, 0, stream>>>(
        Xb, Wqkvt_l, bqkv + (size_t)l * 768, nullptr, QKVb, Vtg, NTOK, 768, 256);
    attn_mfma_kernel<<<dim3(64, 4, 8), 512, 0, stream>>>(
        QKVb, Vtg, amask, ntiles, ordb, Ob);
    hgemm_ln_kernel<<<512, 256, 0, stream>>>(
        Ob, Wot_l, bo + (size_t)l * 256, Xb,
        ln1g + l * 256, ln1b + l * 256, 256);
    hgemm_kernel<1, true><<<dim3(256, 8), 256, 0, stream>>>(
        Xb, W1t_l, b1 + (size_t)l * 1024, nullptr, Hb, nullptr, NTOK, 1024, 256);
    hgemm_ln_kernel<<<512, 256, 0, stream>>>(
        Hb, W2t_l, b2 + (size_t)l * 256, Xb,
        ln2g + l * 256, ln2b + l * 256, 1024);
  }
  lnf_pool_kernel<<<dim3(64, 8), 256, 0, stream>>>(Xb, lnfg, lnfb, amask,
                                                   Pstory);
  poolcls_kernel<<<64, 1024, 0, stream>>>(Xb, Pstory, lenb, sub_idx, sub_cnt,
                                          obj_idx, obj_cnt, mW1, mb1, mW2, mb2,
                                          out);
}

// Round 17
// 677.377 us; speedup vs baseline: 1.0772x; 1.0772x over previous
//
#include <hip/hip_runtime.h>
#include <hip/hip_bf16.h>

// ---------------------------------------------------------------------------
// CLUTRR transformer: B=64 S=512 H=256 L=4 NH=8 DH=32 F=1024 V=50265 K=8 R=25
// Round 17: revert attn grid to R15 (h fastest; b-fastest serialized XCDs).
// Ob layout -> head-major [b][h][s][32]: attention writes contiguous 8KB per
// block (full-line write combining); Wo-projection stages it per-K-tile
// contiguously (template<OHEAD>). poolcls 1024-thread kept from R16.
// ---------------------------------------------------------------------------

typedef __hip_bfloat16 bf16;
typedef __attribute__((ext_vector_type(8))) short short8;
typedef __attribute__((ext_vector_type(4))) float f32x4;

#define S_LEN 512
#define H_DIM 256
#define NTOK  32768      // B*S
#define QSCALE 0.25503488f   // (1/sqrt(32)) * log2(e)

__device__ __forceinline__ void gload_lds16(const void* g, void* l) {
  __builtin_amdgcn_global_load_lds(
      (const __attribute__((address_space(1))) unsigned int*)g,
      (__attribute__((address_space(3))) unsigned int*)l, 16, 0, 0);
}

__device__ __forceinline__ unsigned short f2bu(float x) {
  bf16 t = __float2bfloat16(x);
  return *reinterpret_cast<unsigned short*>(&t);
}
__device__ __forceinline__ float bu2f(unsigned short u) {
  unsigned int x = (unsigned int)u << 16;
  return __uint_as_float(x);
}

// -------- per-batch: exact valid length + tile count --------
__global__ __launch_bounds__(64) void lens_kernel(
    const int* __restrict__ amask, int* __restrict__ ntiles,
    int* __restrict__ lenb) {
  const int b = blockIdx.x, t = threadIdx.x;
  int c = 0;
#pragma unroll
  for (int i = 0; i < 8; ++i) c += amask[b * S_LEN + t + i * 64];
#pragma unroll
  for (int off = 1; off < 64; off <<= 1) c += __shfl_xor(c, off);
  if (t == 0) {
    lenb[b] = c;
    ntiles[b] = (c + 63) >> 6;
  }
}

// -------- rank-sort batches by tile count (descending) --------
__global__ __launch_bounds__(64) void order_kernel(
    const int* __restrict__ ntiles, int* __restrict__ ordb) {
  const int b = threadIdx.x;
  const int ntb = ntiles[b];
  int rank = 0;
  for (int j = 0; j < 64; ++j) {
    const int ntj = __shfl(ntb, j);
    rank += (ntj > ntb) || (ntj == ntb && j < b);
  }
  ordb[rank] = b;
}

// -------- weight cast + transpose: out[N][K] = bf16(in[K][N]) --------
__global__ __launch_bounds__(256) void tcast_kernel(
    const float* __restrict__ in, bf16* __restrict__ out, int K, int N) {
  const int l = blockIdx.z;
  in  += (size_t)l * K * N;
  out += (size_t)l * K * N;
  __shared__ float t[32][33];
  const int n0 = blockIdx.x * 32, k0 = blockIdx.y * 32;
  const int c = threadIdx.x & 31, r = threadIdx.x >> 5;
#pragma unroll
  for (int rr = r; rr < 32; rr += 8)
    t[rr][c] = in[(size_t)(k0 + rr) * N + n0 + c];
  __syncthreads();
#pragma unroll
  for (int rr = r; rr < 32; rr += 8)
    out[(size_t)(n0 + rr) * K + k0 + c] = __float2bfloat16(t[c][rr]);
}

// -------- embedding gather: Xb bf16 only --------
__global__ __launch_bounds__(256) void embed_kernel(
    const int* __restrict__ ids, const float* __restrict__ emb,
    bf16* __restrict__ Xb) {
  size_t i4 = (size_t)blockIdx.x * 256 + threadIdx.x;   // float4 index
  int tok = (int)(i4 >> 6);
  int d4  = (int)(i4 & 63);
  float4 v = *(const float4*)&emb[(size_t)ids[tok] * H_DIM + d4 * 4];
  ushort4 pk;
  pk.x = f2bu(v.x); pk.y = f2bu(v.y); pk.z = f2bu(v.z); pk.w = f2bu(v.w);
  *(ushort4*)&Xb[i4 * 4] = pk;
}

// Staging-source chunk swizzle: lane tid stages 8 elems; LDS pos (tid&3),
// global chunk (tid&3)^((tid>>3)&3). Read side: chunk = g4 ^ ((fr>>1)&3).
#define SRC_CHUNK(tid_) (((tid_) & 3) ^ (((tid_) >> 3) & 3))

// -------- bf16 MFMA GEMM, 2-phase dbuf + LDS-coalesced epilogue --------
// Grid: x = m-tile (fastest -> same-XCD A-panel sharing), y = n-tile.
// MODE 1: bf16 out Cb (w/ optional relu);
// MODE 2: QKV split — n<256 -> Q prescaled; <512 -> K; >=512 -> Vt swizzled.
template<int MODE, bool RELU>
__global__ __launch_bounds__(256) void hgemm_kernel(
    const bf16* __restrict__ A, const bf16* __restrict__ Bt,
    const float* __restrict__ bias, float* __restrict__ Cf,
    bf16* __restrict__ Cb, bf16* __restrict__ Vt,
    int M, int N, int K) {
  // 32KB shared: K-loop staging [2][As 4096 | Bs 4096]; epilogue 128x128 tile
  __shared__ __align__(16) bf16 Sh[16384];
  bf16* const As0 = Sh;          // [2][4096]
  bf16* const Bs0 = Sh + 8192;   // [2][4096]
  const int tid = threadIdx.x;
  const int wv = tid >> 6, ln = tid & 63;
  const int fr = ln & 15, g4 = ln >> 4;
  const int wr = wv >> 1, wc = wv & 1;
  const int m0 = blockIdx.x * 128, n0 = blockIdx.y * 128;
  const int lr = tid >> 2;                     // staging row
  const int lk = SRC_CHUNK(tid) * 8;           // swizzled source k-offset
  const int rc = (g4 ^ ((fr >> 1) & 3)) * 8;   // swizzled read chunk (elems)

#define STAGE_G(buf, kk) do {                                                  \
    const int kof_ = (kk) * 32;                                                \
    gload_lds16(A  + (size_t)(m0 + lr) * K + kof_ + lk,                        \
                &As0[(buf) * 4096 + wv * 512]);                                \
    gload_lds16(A  + (size_t)(m0 + 64 + lr) * K + kof_ + lk,                   \
                &As0[(buf) * 4096 + 2048 + wv * 512]);                         \
    gload_lds16(Bt + (size_t)(n0 + lr) * K + kof_ + lk,                        \
                &Bs0[(buf) * 4096 + wv * 512]);                                \
    gload_lds16(Bt + (size_t)(n0 + 64 + lr) * K + kof_ + lk,                   \
                &Bs0[(buf) * 4096 + 2048 + wv * 512]);                         \
  } while (0)

  f32x4 acc[4][4];
#pragma unroll
  for (int i = 0; i < 4; ++i)
#pragma unroll
    for (int j = 0; j < 4; ++j)
      acc[i][j] = (f32x4){0.f, 0.f, 0.f, 0.f};

  const int NT = K >> 5;
  STAGE_G(0, 0);
  __syncthreads();
  int cur = 0;
  for (int kt = 0; kt < NT; ++kt) {
    if (kt + 1 < NT) STAGE_G(cur ^ 1, kt + 1);
    short8 af[4], bfv[4];
#pragma unroll
    for (int i = 0; i < 4; ++i)
      af[i] = *(const short8*)
          &As0[cur * 4096 + (wr * 64 + i * 16 + fr) * 32 + rc];
#pragma unroll
    for (int j = 0; j < 4; ++j)
      bfv[j] = *(const short8*)
          &Bs0[cur * 4096 + (wc * 64 + j * 16 + fr) * 32 + rc];
#pragma unroll
    for (int i = 0; i < 4; ++i)
#pragma unroll
      for (int j = 0; j < 4; ++j)
        acc[i][j] = __builtin_amdgcn_mfma_f32_16x16x32_bf16(
            af[i], bfv[j], acc[i][j], 0, 0, 0);
    __syncthreads();
    cur ^= 1;
  }
#undef STAGE_G

  // ---- epilogue: stage C tile in LDS (chunk-XOR swizzled), store coalesced
  const bool vpath = (MODE == 2) && (n0 >= 512);
#pragma unroll
  for (int j = 0; j < 4; ++j) {
    const int nl = wc * 64 + j * 16 + fr;
    const int n = n0 + nl;
    const float bv = bias[n];
    const float sc = (MODE == 2 && n < 256) ? QSCALE : 1.0f;
#pragma unroll
    for (int i = 0; i < 4; ++i) {
      const int mlb = wr * 64 + i * 16 + g4 * 4;
#pragma unroll
      for (int r = 0; r < 4; ++r) {
        float o = acc[i][j][r] + bv;
        if (RELU) o = fmaxf(o, 0.f);
        o *= sc;
        const int ml = mlb + r;
        const int addr = vpath ? nl * 128 + (ml ^ ((nl & 7) << 3))
                               : ml * 128 + (nl ^ ((ml & 7) << 3));
        Sh[addr] = __float2bfloat16(o);
      }
    }
  }
  __syncthreads();
  if (!vpath) {
    const int ldc = (MODE == 1) ? N : 768;
#pragma unroll
    for (int p = 0; p < 8; ++p) {
      const int cid = p * 256 + tid;
      const int ml = cid >> 4, mc = cid & 15;
      const short8 v =
          *(const short8*)&Sh[ml * 128 + ((mc * 8) ^ ((ml & 7) << 3))];
      *(short8*)&Cb[(size_t)(m0 + ml) * ldc + n0 + mc * 8] = v;
    }
  } else {
    const int bb = m0 >> 9;
#pragma unroll
    for (int p = 0; p < 8; ++p) {
      const int cid = p * 256 + tid;
      const int ddl = cid >> 4, mc = cid & 15;
      const short8 v =
          *(const short8*)&Sh[ddl * 128 + ((mc * 8) ^ ((ddl & 7) << 3))];
      const int dd = (n0 - 512) + ddl;
      const int hh = dd >> 5, ddd = dd & 31;
      const int s8 = (m0 & 511) + mc * 8;
      const int ssw = (s8 & ~63) | ((s8 & 63) ^ ((ddd & 7) << 3));
      *(short8*)&Vt[(((size_t)bb * 8 + hh) * 32 + ddd) * 512 + ssw] = v;
    }
  }
}

// -------- fused GEMM + bias + residual(bf16) + LayerNorm -> Xb bf16 --------
// OHEAD: A is head-major attention output [b][h][512][32]; K-tile kt = head kt
// whose [64 tok][32 d] sub-block is contiguous. Else A is row-major [M][K].
template<bool OHEAD>
__global__ __launch_bounds__(256) void hgemm_ln_kernel(
    const bf16* __restrict__ A, const bf16* __restrict__ Bt,
    const float* __restrict__ bias, bf16* __restrict__ Xbf,
    const float* __restrict__ g, const float* __restrict__ bt, int K) {
  __shared__ __align__(16) bf16 Sh[20480];     // 40KB
  bf16* const As0 = Sh;                        // [2][2048] (8KB)
  bf16* const Bs0 = Sh + 4096;                 // [2][8192] (32KB)
  // epilogue aliases (staging dead after K-loop):
  float* const rsum = (float*)Sh;              // 256 floats (1KB)
  float* const rsq  = (float*)(Sh + 512);      // 256 floats (1KB)
  bf16*  const XbT  = Sh + 1024;               // [64][256] bf16 (32KB)
  const int tid = threadIdx.x;
  const int wv = tid >> 6;
  const int ln = tid & 63;
  const int fr = ln & 15, g4 = ln >> 4;
  const int m0 = blockIdx.x * 64;
  const int rc = (g4 ^ ((fr >> 1) & 3)) * 8;

#define STAGE_L(buf, kk) do {                                                  \
    const int kof_ = (kk) * 32;                                                \
    if (OHEAD) {                                                               \
      gload_lds16(A + ((size_t)((m0 >> 9) * 8 + (kk)) * 512 + (m0 & 511) +     \
                       (tid >> 2)) * 32 + SRC_CHUNK(tid) * 8,                  \
                  &As0[(buf) * 2048 + wv * 512]);                              \
    } else {                                                                   \
      gload_lds16(A + (size_t)(m0 + (tid >> 2)) * K + kof_ +                   \
                      SRC_CHUNK(tid) * 8,                                      \
                  &As0[(buf) * 2048 + wv * 512]);                              \
    }                                                                          \
    _Pragma("unroll")                                                          \
    for (int e = 0; e < 4; ++e) {                                              \
      const int vt = e * 256 + tid;                                            \
      gload_lds16(Bt + (size_t)(vt >> 2) * K + kof_ + SRC_CHUNK(vt) * 8,       \
                  &Bs0[(buf) * 8192 + e * 2048 + wv * 512]);                   \
    }                                                                          \
  } while (0)

  f32x4 acc[4][4];   // [row frag i][col frag j]
#pragma unroll
  for (int i = 0; i < 4; ++i)
#pragma unroll
    for (int j = 0; j < 4; ++j)
      acc[i][j] = (f32x4){0.f, 0.f, 0.f, 0.f};

  const int NT = K >> 5;
  STAGE_L(0, 0);
  __syncthreads();
  int cur = 0;
  for (int kt = 0; kt < NT; ++kt) {
    if (kt + 1 < NT) STAGE_L(cur ^ 1, kt + 1);
    short8 af[4], bfv[4];
#pragma unroll
    for (int i = 0; i < 4; ++i)
      af[i] = *(const short8*)&As0[cur * 2048 + (i * 16 + fr) * 32 + rc];
#pragma unroll
    for (int j = 0; j < 4; ++j)
      bfv[j] = *(const short8*)
          &Bs0[cur * 8192 + (wv * 64 + j * 16 + fr) * 32 + rc];
#pragma unroll
    for (int i = 0; i < 4; ++i)
#pragma unroll
      for (int j = 0; j < 4; ++j)
        acc[i][j] = __builtin_amdgcn_mfma_f32_16x16x32_bf16(
            af[i], bfv[j], acc[i][j], 0, 0, 0);
    __syncthreads();
    cur ^= 1;
  }
#undef STAGE_L

  // ---- stage residual tile Xbf[m0..m0+63][0..255] into XbT (linear) ----
#pragma unroll
  for (int p = 0; p < 8; ++p) {
    const int seg = p * 4 + wv;   // 32 segments x 512 elems (2 rows each)
    gload_lds16(Xbf + (size_t)(m0 + seg * 2 + (ln >> 5)) * 256 +
                    (ln & 31) * 8,
                &XbT[seg * 512]);
  }
  __syncthreads();

  // ---- bias + residual ----
  float gj[4], bj[4], bsj[4];
#pragma unroll
  for (int j = 0; j < 4; ++j) {
    const int n = wv * 64 + j * 16 + fr;
    gj[j] = g[n]; bj[j] = bt[n]; bsj[j] = bias[n];
  }
#pragma unroll
  for (int i = 0; i < 4; ++i) {
#pragma unroll
    for (int r = 0; r < 4; ++r) {
      const int ml = i * 16 + g4 * 4 + r;
#pragma unroll
      for (int j = 0; j < 4; ++j) {
        const int nl = wv * 64 + j * 16 + fr;
        acc[i][j][r] += bsj[j] +
            bu2f(*(const unsigned short*)&XbT[ml * 256 + nl]);
      }
    }
  }
  // ---- LN stats ----
#pragma unroll
  for (int i = 0; i < 4; ++i) {
#pragma unroll
    for (int r = 0; r < 4; ++r) {
      float sp = acc[i][0][r] + acc[i][1][r] + acc[i][2][r] + acc[i][3][r];
      float qp = acc[i][0][r] * acc[i][0][r] + acc[i][1][r] * acc[i][1][r] +
                 acc[i][2][r] * acc[i][2][r] + acc[i][3][r] * acc[i][3][r];
#pragma unroll
      for (int off = 1; off < 16; off <<= 1) {
        sp += __shfl_xor(sp, off);
        qp += __shfl_xor(qp, off);
      }
      if (fr == 0) {
        const int ri = i * 16 + g4 * 4 + r;
        rsum[wv * 64 + ri] = sp;
        rsq[wv * 64 + ri] = qp;
      }
    }
  }
  __syncthreads();
  // ---- normalize + write swizzled bf16 tile ----
#pragma unroll
  for (int i = 0; i < 4; ++i) {
#pragma unroll
    for (int r = 0; r < 4; ++r) {
      const int ri = i * 16 + g4 * 4 + r;
      const float tot = rsum[ri] + rsum[64 + ri] + rsum[128 + ri] +
                        rsum[192 + ri];
      const float tq = rsq[ri] + rsq[64 + ri] + rsq[128 + ri] + rsq[192 + ri];
      const float mu = tot * (1.0f / 256.0f);
      const float var = tq * (1.0f / 256.0f) - mu * mu;
      const float rstd = rsqrtf(var + 1e-5f);
#pragma unroll
      for (int j = 0; j < 4; ++j) {
        const int nl = wv * 64 + j * 16 + fr;
        const float o = (acc[i][j][r] - mu) * rstd * gj[j] + bj[j];
        XbT[ri * 256 + (nl ^ ((ri & 7) << 3))] = __float2bfloat16(o);
      }
    }
  }
  __syncthreads();
#pragma unroll
  for (int p = 0; p < 8; ++p) {
    const int c8 = p * 256 + tid;
    const int row = c8 >> 5, cc = c8 & 31;
    const short8 v =
        *(const short8*)&XbT[row * 256 + ((cc * 8) ^ ((row & 7) << 3))];
    *(short8*)&Xbf[(size_t)(m0 + row) * 256 + cc * 8] = v;
  }
}

// -------- bf16 MFMA flash attention: 512 threads, 8 waves, 128 q-rows ------
// Grid (h fastest, qg, b) — R15 form. Ob head-major [b][h][512][32]:
// each block writes a contiguous 8KB region (full-line write combining).
__global__ __launch_bounds__(512, 8) void attn_mfma_kernel(
    const bf16* __restrict__ QKVb, const bf16* __restrict__ Vt,
    const int* __restrict__ amask, const int* __restrict__ ntiles,
    const int* __restrict__ ordb, bf16* __restrict__ Ob) {
  const int b = ordb[blockIdx.z];
  const int h = blockIdx.x;          // fastest dim
  const int qg = blockIdx.y;         // 0..3 -> q rows qg*128..+127
  const int tid = threadIdx.x;       // 0..511
  const int wv = tid >> 6, ln = tid & 63;
  const int fr = ln & 15, g4 = ln >> 4;
  const int f8 = (fr & 7) << 3;
  const int rc = (g4 ^ ((fr >> 1) & 3)) * 8;   // swizzled K/Q read chunk
  const int bh32 = (b * 8 + h) * 32;
  __shared__ __align__(16) bf16 Ks[2][2048];   // [buf][64][32], chunk-swz
  __shared__ __align__(16) bf16 Vs[2][2048];   // [buf][32 d][64 k] swizzled
  __shared__ __align__(16) bf16 Ps[8192];      // Q staging (128x32); then
                                               // 8 per-wave P tiles [16][64]
  __shared__ __align__(16) float Ms[64];

  const int nt = ntiles[b];

#define STAGE_A(buf, kt_) do {                                                 \
    if (tid < 256) {                                                           \
      const int k0_ = (kt_) * 64;                                              \
      gload_lds16(QKVb + (size_t)(b * S_LEN + k0_ + (tid >> 2)) * 768 + 256 +  \
                      h * 32 + SRC_CHUNK(tid) * 8,                             \
                  &Ks[(buf)][wv * 512]);                                       \
      gload_lds16(Vt + (size_t)(bh32 + (tid >> 3)) * 512 + k0_ +               \
                      (tid & 7) * 8,                                           \
                  &Vs[(buf)][wv * 512]);                                       \
      if ((kt_) == nt - 1 && tid < 64)                                         \
        Ms[tid] = (amask[b * S_LEN + k0_ + tid] != 0) ? 0.f : -1e9f;           \
    }                                                                          \
  } while (0)

  // stage 128 Q rows into Ps[0..4095] (wave w -> rows w*16..+15)
  gload_lds16(QKVb + (size_t)(b * S_LEN + qg * 128 + (tid >> 2)) * 768 +
                  h * 32 + SRC_CHUNK(tid) * 8,
              &Ps[wv * 512]);
  STAGE_A(0, 0);
  __syncthreads();
  const short8 qb = *(const short8*)&Ps[wv * 512 + fr * 32 + rc];
  __syncthreads();   // all Q-frag reads done before any P write

  f32x4 accO[2];
  accO[0] = (f32x4){0.f, 0.f, 0.f, 0.f};
  accO[1] = (f32x4){0.f, 0.f, 0.f, 0.f};
  float mrun = -1e30f, lrun = 0.f;   // per-lane state for q = fr (log2 domain)
  const int srcq = 20 * g4;   // shfl src base: lane 16*g4 + (4*g4 + rr)

  int cur = 0;
  for (int kt = 0; kt < nt; ++kt) {
    if (kt + 1 < nt) STAGE_A(cur ^ 1, kt + 1);
    const bool bnd = (kt == nt - 1);

    // S^T = K @ Q^T : 4 MFMAs cover 64 k x 16 q (already log2-scaled via Q)
    f32x4 st[4];
#pragma unroll
    for (int kb = 0; kb < 4; ++kb) {
      const short8 kf = *(const short8*)&Ks[cur][(kb * 16 + fr) * 32 + rc];
      f32x4 z = (f32x4){0.f, 0.f, 0.f, 0.f};
      st[kb] = __builtin_amdgcn_mfma_f32_16x16x32_bf16(kf, qb, z, 0, 0, 0);
    }

    float p[16];
    if (bnd) {
#pragma unroll
      for (int kb = 0; kb < 4; ++kb) {
        const f32x4 mv = ((const f32x4*)Ms)[kb * 4 + g4];
#pragma unroll
        for (int rr = 0; rr < 4; ++rr) p[kb * 4 + rr] = st[kb][rr] + mv[rr];
      }
    } else {
#pragma unroll
      for (int kb = 0; kb < 4; ++kb)
#pragma unroll
        for (int rr = 0; rr < 4; ++rr) p[kb * 4 + rr] = st[kb][rr];
    }

    // max: v_max3 tree (depth 3) + 2 cross-lane
    const float a0 = fmaxf(fmaxf(p[0], p[1]), p[2]);
    const float a1 = fmaxf(fmaxf(p[3], p[4]), p[5]);
    const float a2 = fmaxf(fmaxf(p[6], p[7]), p[8]);
    const float a3 = fmaxf(fmaxf(p[9], p[10]), p[11]);
    const float a4 = fmaxf(fmaxf(p[12], p[13]), p[14]);
    float mx = fmaxf(fmaxf(fmaxf(a0, a1), fmaxf(a2, a3)), fmaxf(a4, p[15]));
    mx = fmaxf(mx, __shfl_xor(mx, 16));
    mx = fmaxf(mx, __shfl_xor(mx, 32));

    // defer-max (T13): rescale only when the row max grew by > 8 (log2)
    float corr = 1.f;
    if (!__all(mx <= mrun + 8.f)) {
      const float mnew = fmaxf(mrun, mx);
      corr = exp2f(mrun - mnew);
      mrun = mnew;
#pragma unroll
      for (int rr = 0; rr < 4; ++rr) {
        const float cs = __shfl(corr, srcq + rr);
        accO[0][rr] *= cs;
        accO[1][rr] *= cs;
      }
    }

#pragma unroll
    for (int i = 0; i < 16; ++i) p[i] = exp2f(p[i] - mrun);
    // pairwise-tree sum (depth 4) + 2 cross-lane
    const float b0 = p[0] + p[1], b1 = p[2] + p[3], b2 = p[4] + p[5],
                b3 = p[6] + p[7], b4 = p[8] + p[9], b5 = p[10] + p[11],
                b6 = p[12] + p[13], b7 = p[14] + p[15];
    float ps = ((b0 + b1) + (b2 + b3)) + ((b4 + b5) + (b6 + b7));
    ps += __shfl_xor(ps, 16);
    ps += __shfl_xor(ps, 32);
    lrun = lrun * corr + ps;

    // write P rows: lane writes 4 shorts per kb at k = kb*16 + g4*4, XOR-swz
#pragma unroll
    for (int kb = 0; kb < 4; ++kb) {
      ushort4 w4;
      w4.x = f2bu(p[kb * 4 + 0]);
      w4.y = f2bu(p[kb * 4 + 1]);
      w4.z = f2bu(p[kb * 4 + 2]);
      w4.w = f2bu(p[kb * 4 + 3]);
      *(ushort4*)&Ps[wv * 1024 + fr * 64 + ((kb * 16 + g4 * 4) ^ f8)] = w4;
    }

    // PV: O[q][d] += P[16q x 32k] @ V[32k x 16d], per-wave (no barrier)
#pragma unroll
    for (int kk = 0; kk < 2; ++kk) {
      const short8 pa = *(const short8*)
          &Ps[wv * 1024 + fr * 64 + ((kk * 32 + g4 * 8) ^ f8)];
#pragma unroll
      for (int df = 0; df < 2; ++df) {
        const short8 vb = *(const short8*)
            &Vs[cur][(df * 16 + fr) * 64 + ((kk * 32 + g4 * 8) ^ f8)];
        accO[df] = __builtin_amdgcn_mfma_f32_16x16x32_bf16(
            pa, vb, accO[df], 0, 0, 0);
      }
    }
    __syncthreads();
    cur ^= 1;
  }
#undef STAGE_A

  const float inv = 1.0f / lrun;   // q = fr layout
#pragma unroll
  for (int rr = 0; rr < 4; ++rr) {
    const float iv = __shfl(inv, srcq + rr);
    const int q = qg * 128 + wv * 16 + g4 * 4 + rr;
    const size_t orow = ((size_t)(b * 8 + h) * S_LEN + q) * 32;  // head-major
    Ob[orow + fr]      = __float2bfloat16(accO[0][rr] * iv);
    Ob[orow + 16 + fr] = __float2bfloat16(accO[1][rr] * iv);
  }
}

// -------- fused final-LN + story-pool stage1 (bf16 stream) --------
__global__ __launch_bounds__(256) void lnf_pool_kernel(
    bf16* __restrict__ Xbf, const float* __restrict__ g,
    const float* __restrict__ bt, const int* __restrict__ amask,
    float* __restrict__ Pstory) {
  const int b = blockIdx.x, sg = blockIdx.y;
  const int tid = threadIdx.x, wv = tid >> 6, ln = tid & 63;
  const float4 gg = ((const float4*)g)[ln];
  const float4 bb = ((const float4*)bt)[ln];
  float ax = 0.f, ay = 0.f, az = 0.f, aw = 0.f;
  for (int t = wv; t < 64; t += 4) {
    const size_t tok = (size_t)b * S_LEN + sg * 64 + t;
    const ushort4 u = *(const ushort4*)&Xbf[tok * 256 + ln * 4];
    const float vx = bu2f(u.x), vy = bu2f(u.y), vz = bu2f(u.z),
                vw = bu2f(u.w);
    float s = vx + vy + vz + vw;
#pragma unroll
    for (int off = 1; off < 64; off <<= 1) s += __shfl_xor(s, off);
    const float mu = s * (1.0f / 256.0f);
    const float dx = vx - mu, dy = vy - mu, dz = vz - mu, dw = vw - mu;
    float sq = dx * dx + dy * dy + dz * dz + dw * dw;
#pragma unroll
    for (int off = 1; off < 64; off <<= 1) sq += __shfl_xor(sq, off);
    const float rstd = rsqrtf(sq * (1.0f / 256.0f) + 1e-5f);
    const float ox = dx * rstd * gg.x + bb.x;
    const float oy = dy * rstd * gg.y + bb.y;
    const float oz = dz * rstd * gg.z + bb.z;
    const float ow = dw * rstd * gg.w + bb.w;
    ushort4 o4;
    o4.x = f2bu(ox); o4.y = f2bu(oy); o4.z = f2bu(oz); o4.w = f2bu(ow);
    *(ushort4*)&Xbf[tok * 256 + ln * 4] = o4;
    if (amask[tok]) { ax += ox; ay += oy; az += oz; aw += ow; }
  }
  __shared__ float part[4][256];
  part[wv][ln * 4 + 0] = ax;
  part[wv][ln * 4 + 1] = ay;
  part[wv][ln * 4 + 2] = az;
  part[wv][ln * 4 + 3] = aw;
  __syncthreads();
  const float tot = part[0][tid] + part[1][tid] + part[2][tid] + part[3][tid];
  Pstory[((size_t)b * 8 + sg) * 256 + tid] = tot;
}

// -------- pool combine + classifier: 1024 threads, split k-loop --------
__global__ __launch_bounds__(1024) void poolcls_kernel(
    const bf16* __restrict__ Xbf, const float* __restrict__ Pstory,
    const int* __restrict__ lenb,
    const int* __restrict__ sub_idx, const int* __restrict__ sub_cnt,
    const int* __restrict__ obj_idx, const int* __restrict__ obj_cnt,
    const float* __restrict__ mW1, const float* __restrict__ mb1,
    const float* __restrict__ mW2, const float* __restrict__ mb2,
    float* __restrict__ out) {
  const int b = blockIdx.x, tid = threadIdx.x;
  const int t = tid & 255, sl = tid >> 8;   // channel, slice 0-3
  __shared__ float fs[768];
  __shared__ float part[4][256];
  __shared__ float hid[256];
  __shared__ float w2s[256 * 25];
  const bf16* xb = Xbf + (size_t)b * S_LEN * H_DIM;
  // stage mW2 (25.6KB) while computing fs
  for (int i = tid; i < 6400; i += 1024) w2s[i] = mW2[i];
  if (sl == 0) {
    float s = 0.f;
#pragma unroll
    for (int i = 0; i < 8; ++i) s += Pstory[((size_t)b * 8 + i) * 256 + t];
    fs[512 + t] = s / (float)lenb[b];   // len >= 16
  } else if (sl == 1) {
    const int cc = sub_cnt[b];
    float s2 = 0.f;
    for (int j = 0; j < cc; ++j)
      s2 += __bfloat162float(xb[(size_t)sub_idx[b * 8 + j] * H_DIM + t]);
    fs[t] = (cc > 0) ? s2 / (float)cc : 0.f;
  } else if (sl == 2) {
    const int cc = obj_cnt[b];
    float s2 = 0.f;
    for (int j = 0; j < cc; ++j)
      s2 += __bfloat162float(xb[(size_t)obj_idx[b * 8 + j] * H_DIM + t]);
    fs[256 + t] = (cc > 0) ? s2 / (float)cc : 0.f;
  }
  __syncthreads();
  // hidden GEMM: slice sl covers k in [sl*192, sl*192+192)
  float acc = 0.f;
  for (int k = sl * 192; k < sl * 192 + 192; ++k)
    acc += fs[k] * mW1[(size_t)k * 256 + t];
  part[sl][t] = acc;
  __syncthreads();
  if (sl == 0)
    hid[t] = fmaxf(part[0][t] + part[1][t] + part[2][t] + part[3][t] +
                       mb1[t],
                   0.f);
  __syncthreads();
  if (tid < 25) {
    float o = mb2[tid];
    for (int j = 0; j < 256; ++j) o += hid[j] * w2s[j * 25 + tid];
    out[b * 25 + tid] = o;
  }
}

// ---------------------------------------------------------------------------
extern "C" void kernel_launch(void* const* d_in, const int* in_sizes, int n_in,
                              void* d_out, int out_size, void* d_ws, size_t ws_size,
                              hipStream_t stream) {
  const int*   input_ids = (const int*)d_in[0];
  const int*   amask     = (const int*)d_in[1];
  const int*   sub_idx   = (const int*)d_in[2];
  const int*   sub_cnt   = (const int*)d_in[3];
  const int*   obj_idx   = (const int*)d_in[4];
  const int*   obj_cnt   = (const int*)d_in[5];
  const float* emb  = (const float*)d_in[6];
  const float* Wqkv = (const float*)d_in[7];
  const float* bqkv = (const float*)d_in[8];
  const float* Wo   = (const float*)d_in[9];
  const float* bo   = (const float*)d_in[10];
  const float* ln1g = (const float*)d_in[11];
  const float* ln1b = (const float*)d_in[12];
  const float* ln2g = (const float*)d_in[13];
  const float* ln2b = (const float*)d_in[14];
  const float* W1   = (const float*)d_in[15];
  const float* b1   = (const float*)d_in[16];
  const float* W2   = (const float*)d_in[17];
  const float* b2   = (const float*)d_in[18];
  const float* lnfg = (const float*)d_in[19];
  const float* lnfb = (const float*)d_in[20];
  const float* mW1  = (const float*)d_in[21];
  const float* mb1  = (const float*)d_in[22];
  const float* mW2  = (const float*)d_in[23];
  const float* mb2  = (const float*)d_in[24];
  float* out = (float*)d_out;

  // workspace layout (bytes)
  char* w = (char*)d_ws;
  bf16*  Xb   = (bf16*)w;                          w += (size_t)NTOK * 256 * 2;  // 16.8MB
  bf16*  QKVb = (bf16*)w;                          w += (size_t)NTOK * 768 * 2;  // 50.3MB
  bf16*  Vtg  = (bf16*)w;                          w += (size_t)NTOK * 256 * 2;  // 16.8MB
  bf16*  Ob   = (bf16*)w;                          w += (size_t)NTOK * 256 * 2;  // 16.8MB
  bf16*  Wqkvt= (bf16*)w;                          w += (size_t)4 * 768 * 256 * 2;
  bf16*  Wot  = (bf16*)w;                          w += (size_t)4 * 256 * 256 * 2;
  bf16*  W1t  = (bf16*)w;                          w += (size_t)4 * 1024 * 256 * 2;
  bf16*  W2t  = (bf16*)w;                          w += (size_t)4 * 256 * 1024 * 2;
  float* Pstory = (float*)w;                       w += (size_t)64 * 8 * 256 * 4;
  int*   ntiles = (int*)w;                         w += 256;
  int*   lenb   = (int*)w;                         w += 256;
  int*   ordb   = (int*)w;                         w += 256;
  bf16*  Hb   = QKVb;   // aliases [QKVb, Vtg] = 67.1MB >= 32768*1024*2

  lens_kernel<<<64, 64, 0, stream>>>(amask, ntiles, lenb);
  order_kernel<<<1, 64, 0, stream>>>(ntiles, ordb);
  tcast_kernel<<<dim3(24, 8, 4), 256, 0, stream>>>(Wqkv, Wqkvt, 256, 768);
  tcast_kernel<<<dim3(8, 8, 4), 256, 0, stream>>>(Wo, Wot, 256, 256);
  tcast_kernel<<<dim3(32, 8, 4), 256, 0, stream>>>(W1, W1t, 256, 1024);
  tcast_kernel<<<dim3(8, 32, 4), 256, 0, stream>>>(W2, W2t, 1024, 256);

  embed_kernel<<<8192, 256, 0, stream>>>(input_ids, emb, Xb);

  for (int l = 0; l < 4; ++l) {
    const bf16* Wqkvt_l = Wqkvt + (size_t)l * 768 * 256;
    const bf16* Wot_l   = Wot + (size_t)l * 256 * 256;
    const bf16* W1t_l   = W1t + (size_t)l * 1024 * 256;
    const bf16* W2t_l   = W2t + (size_t)l * 256 * 1024;

    hgemm_kernel<2, false><<<dim3(256, 6), 256, 0, stream>>>(
        Xb, Wqkvt_l, bqkv + (size_t)l * 768, nullptr, QKVb, Vtg, NTOK, 768, 256);
    attn_mfma_kernel<<<dim3(8, 4, 64), 512, 0, stream>>>(
        QKVb, Vtg, amask, ntiles, ordb, Ob);
    hgemm_ln_kernel<true><<<512, 256, 0, stream>>>(
        Ob, Wot_l, bo + (size_t)l * 256, Xb,
        ln1g + l * 256, ln1b + l * 256, 256);
    hgemm_kernel<1, true><<<dim3(256, 8), 256, 0, stream>>>(
        Xb, W1t_l, b1 + (size_t)l * 1024, nullptr, Hb, nullptr, NTOK, 1024, 256);
    hgemm_ln_kernel<false><<<512, 256, 0, stream>>>(
        Hb, W2t_l, b2 + (size_t)l * 256, Xb,
        ln2g + l * 256, ln2b + l * 256, 1024);
  }
  lnf_pool_kernel<<<dim3(64, 8), 256, 0, stream>>>(Xb, lnfg, lnfb, amask,
                                                   Pstory);
  poolcls_kernel<<<64, 1024, 0, stream>>>(Xb, Pstory, lenb, sub_idx, sub_cnt,
                                          obj_idx, obj_cnt, mW1, mb1, mW2, mb2,
                                          out);
}

// Round 18
// 676.101 us; speedup vs baseline: 1.0793x; 1.0019x over previous
//
#include <hip/hip_runtime.h>
#include <hip/hip_bf16.h>

// ---------------------------------------------------------------------------
// CLUTRR transformer: B=64 S=512 H=256 L=4 NH=8 DH=32 F=1024 V=50265 K=8 R=25
// Round 18: head-major Q/K layout [b][h][512][32] (like Ob in R17) — full
// cache-line fetch efficiency in attention staging; QKV epilogue routes
// Q/K head-major. Hb aliases [Qh,Kh,Vtg,Ob]. Rest identical to R17 (677 us).
// ---------------------------------------------------------------------------

typedef __hip_bfloat16 bf16;
typedef __attribute__((ext_vector_type(8))) short short8;
typedef __attribute__((ext_vector_type(4))) float f32x4;

#define S_LEN 512
#define H_DIM 256
#define NTOK  32768      // B*S
#define QSCALE 0.25503488f   // (1/sqrt(32)) * log2(e)

__device__ __forceinline__ void gload_lds16(const void* g, void* l) {
  __builtin_amdgcn_global_load_lds(
      (const __attribute__((address_space(1))) unsigned int*)g,
      (__attribute__((address_space(3))) unsigned int*)l, 16, 0, 0);
}

__device__ __forceinline__ unsigned short f2bu(float x) {
  bf16 t = __float2bfloat16(x);
  return *reinterpret_cast<unsigned short*>(&t);
}
__device__ __forceinline__ float bu2f(unsigned short u) {
  unsigned int x = (unsigned int)u << 16;
  return __uint_as_float(x);
}

// -------- per-batch: exact valid length + tile count --------
__global__ __launch_bounds__(64) void lens_kernel(
    const int* __restrict__ amask, int* __restrict__ ntiles,
    int* __restrict__ lenb) {
  const int b = blockIdx.x, t = threadIdx.x;
  int c = 0;
#pragma unroll
  for (int i = 0; i < 8; ++i) c += amask[b * S_LEN + t + i * 64];
#pragma unroll
  for (int off = 1; off < 64; off <<= 1) c += __shfl_xor(c, off);
  if (t == 0) {
    lenb[b] = c;
    ntiles[b] = (c + 63) >> 6;
  }
}

// -------- rank-sort batches by tile count (descending) --------
__global__ __launch_bounds__(64) void order_kernel(
    const int* __restrict__ ntiles, int* __restrict__ ordb) {
  const int b = threadIdx.x;
  const int ntb = ntiles[b];
  int rank = 0;
  for (int j = 0; j < 64; ++j) {
    const int ntj = __shfl(ntb, j);
    rank += (ntj > ntb) || (ntj == ntb && j < b);
  }
  ordb[rank] = b;
}

// -------- weight cast + transpose: out[N][K] = bf16(in[K][N]) --------
__global__ __launch_bounds__(256) void tcast_kernel(
    const float* __restrict__ in, bf16* __restrict__ out, int K, int N) {
  const int l = blockIdx.z;
  in  += (size_t)l * K * N;
  out += (size_t)l * K * N;
  __shared__ float t[32][33];
  const int n0 = blockIdx.x * 32, k0 = blockIdx.y * 32;
  const int c = threadIdx.x & 31, r = threadIdx.x >> 5;
#pragma unroll
  for (int rr = r; rr < 32; rr += 8)
    t[rr][c] = in[(size_t)(k0 + rr) * N + n0 + c];
  __syncthreads();
#pragma unroll
  for (int rr = r; rr < 32; rr += 8)
    out[(size_t)(n0 + rr) * K + k0 + c] = __float2bfloat16(t[c][rr]);
}

// -------- embedding gather: Xb bf16 only --------
__global__ __launch_bounds__(256) void embed_kernel(
    const int* __restrict__ ids, const float* __restrict__ emb,
    bf16* __restrict__ Xb) {
  size_t i4 = (size_t)blockIdx.x * 256 + threadIdx.x;   // float4 index
  int tok = (int)(i4 >> 6);
  int d4  = (int)(i4 & 63);
  float4 v = *(const float4*)&emb[(size_t)ids[tok] * H_DIM + d4 * 4];
  ushort4 pk;
  pk.x = f2bu(v.x); pk.y = f2bu(v.y); pk.z = f2bu(v.z); pk.w = f2bu(v.w);
  *(ushort4*)&Xb[i4 * 4] = pk;
}

// Staging-source chunk swizzle: lane tid stages 8 elems; LDS pos (tid&3),
// global chunk (tid&3)^((tid>>3)&3). Read side: chunk = g4 ^ ((fr>>1)&3).
#define SRC_CHUNK(tid_) (((tid_) & 3) ^ (((tid_) >> 3) & 3))

// -------- bf16 MFMA GEMM, 2-phase dbuf + LDS-coalesced epilogue --------
// Grid: x = m-tile (fastest -> same-XCD A-panel sharing), y = n-tile.
// MODE 1: bf16 out Cb (w/ optional relu), row-major [M][N];
// MODE 2: QKV split — n<256 -> Qh head-major (prescaled); n<512 -> Kh
//         head-major; n>=512 -> Vt [b,h,d,s^swz].
template<int MODE, bool RELU>
__global__ __launch_bounds__(256) void hgemm_kernel(
    const bf16* __restrict__ A, const bf16* __restrict__ Bt,
    const float* __restrict__ bias, bf16* __restrict__ Cb,
    bf16* __restrict__ Kb, bf16* __restrict__ Vt,
    int M, int N, int K) {
  // 32KB shared: K-loop staging [2][As 4096 | Bs 4096]; epilogue 128x128 tile
  __shared__ __align__(16) bf16 Sh[16384];
  bf16* const As0 = Sh;          // [2][4096]
  bf16* const Bs0 = Sh + 8192;   // [2][4096]
  const int tid = threadIdx.x;
  const int wv = tid >> 6, ln = tid & 63;
  const int fr = ln & 15, g4 = ln >> 4;
  const int wr = wv >> 1, wc = wv & 1;
  const int m0 = blockIdx.x * 128, n0 = blockIdx.y * 128;
  const int lr = tid >> 2;                     // staging row
  const int lk = SRC_CHUNK(tid) * 8;           // swizzled source k-offset
  const int rc = (g4 ^ ((fr >> 1) & 3)) * 8;   // swizzled read chunk (elems)

#define STAGE_G(buf, kk) do {                                                  \
    const int kof_ = (kk) * 32;                                                \
    gload_lds16(A  + (size_t)(m0 + lr) * K + kof_ + lk,                        \
                &As0[(buf) * 4096 + wv * 512]);                                \
    gload_lds16(A  + (size_t)(m0 + 64 + lr) * K + kof_ + lk,                   \
                &As0[(buf) * 4096 + 2048 + wv * 512]);                         \
    gload_lds16(Bt + (size_t)(n0 + lr) * K + kof_ + lk,                        \
                &Bs0[(buf) * 4096 + wv * 512]);                                \
    gload_lds16(Bt + (size_t)(n0 + 64 + lr) * K + kof_ + lk,                   \
                &Bs0[(buf) * 4096 + 2048 + wv * 512]);                         \
  } while (0)

  f32x4 acc[4][4];
#pragma unroll
  for (int i = 0; i < 4; ++i)
#pragma unroll
    for (int j = 0; j < 4; ++j)
      acc[i][j] = (f32x4){0.f, 0.f, 0.f, 0.f};

  const int NT = K >> 5;
  STAGE_G(0, 0);
  __syncthreads();
  int cur = 0;
  for (int kt = 0; kt < NT; ++kt) {
    if (kt + 1 < NT) STAGE_G(cur ^ 1, kt + 1);
    short8 af[4], bfv[4];
#pragma unroll
    for (int i = 0; i < 4; ++i)
      af[i] = *(const short8*)
          &As0[cur * 4096 + (wr * 64 + i * 16 + fr) * 32 + rc];
#pragma unroll
    for (int j = 0; j < 4; ++j)
      bfv[j] = *(const short8*)
          &Bs0[cur * 4096 + (wc * 64 + j * 16 + fr) * 32 + rc];
#pragma unroll
    for (int i = 0; i < 4; ++i)
#pragma unroll
      for (int j = 0; j < 4; ++j)
        acc[i][j] = __builtin_amdgcn_mfma_f32_16x16x32_bf16(
            af[i], bfv[j], acc[i][j], 0, 0, 0);
    __syncthreads();
    cur ^= 1;
  }
#undef STAGE_G

  // ---- epilogue: stage C tile in LDS (chunk-XOR swizzled), store coalesced
  const bool vpath = (MODE == 2) && (n0 >= 512);
#pragma unroll
  for (int j = 0; j < 4; ++j) {
    const int nl = wc * 64 + j * 16 + fr;
    const int n = n0 + nl;
    const float bv = bias[n];
    const float sc = (MODE == 2 && n < 256) ? QSCALE : 1.0f;
#pragma unroll
    for (int i = 0; i < 4; ++i) {
      const int mlb = wr * 64 + i * 16 + g4 * 4;
#pragma unroll
      for (int r = 0; r < 4; ++r) {
        float o = acc[i][j][r] + bv;
        if (RELU) o = fmaxf(o, 0.f);
        o *= sc;
        const int ml = mlb + r;
        const int addr = vpath ? nl * 128 + (ml ^ ((nl & 7) << 3))
                               : ml * 128 + (nl ^ ((ml & 7) << 3));
        Sh[addr] = __float2bfloat16(o);
      }
    }
  }
  __syncthreads();
  if (MODE == 1) {
#pragma unroll
    for (int p = 0; p < 8; ++p) {
      const int cid = p * 256 + tid;
      const int ml = cid >> 4, mc = cid & 15;
      const short8 v =
          *(const short8*)&Sh[ml * 128 + ((mc * 8) ^ ((ml & 7) << 3))];
      *(short8*)&Cb[(size_t)(m0 + ml) * N + n0 + mc * 8] = v;
    }
  } else if (!vpath) {
    // Q/K head-major: target = (Q or K)[((b*8+hh)*512 + s)*32 + dd]
    const int bb = m0 >> 9, s0 = m0 & 511;
    const bool isK = (n0 >= 256);
    bf16* const dst = isK ? Kb : Cb;
    const int hbase = (n0 - (isK ? 256 : 0)) >> 5;
#pragma unroll
    for (int p = 0; p < 8; ++p) {
      const int cid = p * 256 + tid;
      const int ml = cid >> 4, mc = cid & 15;
      const short8 v =
          *(const short8*)&Sh[ml * 128 + ((mc * 8) ^ ((ml & 7) << 3))];
      const int hh = hbase + (mc >> 2);
      const int dd = (mc & 3) * 8;
      *(short8*)&dst[(((size_t)(bb * 8 + hh) * 512) + s0 + ml) * 32 + dd] = v;
    }
  } else {
    const int bb = m0 >> 9;
#pragma unroll
    for (int p = 0; p < 8; ++p) {
      const int cid = p * 256 + tid;
      const int ddl = cid >> 4, mc = cid & 15;
      const short8 v =
          *(const short8*)&Sh[ddl * 128 + ((mc * 8) ^ ((ddl & 7) << 3))];
      const int dd = (n0 - 512) + ddl;
      const int hh = dd >> 5, ddd = dd & 31;
      const int s8 = (m0 & 511) + mc * 8;
      const int ssw = (s8 & ~63) | ((s8 & 63) ^ ((ddd & 7) << 3));
      *(short8*)&Vt[(((size_t)bb * 8 + hh) * 32 + ddd) * 512 + ssw] = v;
    }
  }
}

// -------- fused GEMM + bias + residual(bf16) + LayerNorm -> Xb bf16 --------
// OHEAD: A is head-major attention output [b][h][512][32]; K-tile kt = head kt
// whose [64 tok][32 d] sub-block is contiguous. Else A is row-major [M][K].
template<bool OHEAD>
__global__ __launch_bounds__(256) void hgemm_ln_kernel(
    const bf16* __restrict__ A, const bf16* __restrict__ Bt,
    const float* __restrict__ bias, bf16* __restrict__ Xbf,
    const float* __restrict__ g, const float* __restrict__ bt, int K) {
  __shared__ __align__(16) bf16 Sh[20480];     // 40KB
  bf16* const As0 = Sh;                        // [2][2048] (8KB)
  bf16* const Bs0 = Sh + 4096;                 // [2][8192] (32KB)
  // epilogue aliases (staging dead after K-loop):
  float* const rsum = (float*)Sh;              // 256 floats (1KB)
  float* const rsq  = (float*)(Sh + 512);      // 256 floats (1KB)
  bf16*  const XbT  = Sh + 1024;               // [64][256] bf16 (32KB)
  const int tid = threadIdx.x;
  const int wv = tid >> 6;
  const int ln = tid & 63;
  const int fr = ln & 15, g4 = ln >> 4;
  const int m0 = blockIdx.x * 64;
  const int rc = (g4 ^ ((fr >> 1) & 3)) * 8;

#define STAGE_L(buf, kk) do {                                                  \
    const int kof_ = (kk) * 32;                                                \
    if (OHEAD) {                                                               \
      gload_lds16(A + ((size_t)((m0 >> 9) * 8 + (kk)) * 512 + (m0 & 511) +     \
                       (tid >> 2)) * 32 + SRC_CHUNK(tid) * 8,                  \
                  &As0[(buf) * 2048 + wv * 512]);                              \
    } else {                                                                   \
      gload_lds16(A + (size_t)(m0 + (tid >> 2)) * K + kof_ +                   \
                      SRC_CHUNK(tid) * 8,                                      \
                  &As0[(buf) * 2048 + wv * 512]);                              \
    }                                                                          \
    _Pragma("unroll")                                                          \
    for (int e = 0; e < 4; ++e) {                                              \
      const int vt = e * 256 + tid;                                            \
      gload_lds16(Bt + (size_t)(vt >> 2) * K + kof_ + SRC_CHUNK(vt) * 8,       \
                  &Bs0[(buf) * 8192 + e * 2048 + wv * 512]);                   \
    }                                                                          \
  } while (0)

  f32x4 acc[4][4];   // [row frag i][col frag j]
#pragma unroll
  for (int i = 0; i < 4; ++i)
#pragma unroll
    for (int j = 0; j < 4; ++j)
      acc[i][j] = (f32x4){0.f, 0.f, 0.f, 0.f};

  const int NT = K >> 5;
  STAGE_L(0, 0);
  __syncthreads();
  int cur = 0;
  for (int kt = 0; kt < NT; ++kt) {
    if (kt + 1 < NT) STAGE_L(cur ^ 1, kt + 1);
    short8 af[4], bfv[4];
#pragma unroll
    for (int i = 0; i < 4; ++i)
      af[i] = *(const short8*)&As0[cur * 2048 + (i * 16 + fr) * 32 + rc];
#pragma unroll
    for (int j = 0; j < 4; ++j)
      bfv[j] = *(const short8*)
          &Bs0[cur * 8192 + (wv * 64 + j * 16 + fr) * 32 + rc];
#pragma unroll
    for (int i = 0; i < 4; ++i)
#pragma unroll
      for (int j = 0; j < 4; ++j)
        acc[i][j] = __builtin_amdgcn_mfma_f32_16x16x32_bf16(
            af[i], bfv[j], acc[i][j], 0, 0, 0);
    __syncthreads();
    cur ^= 1;
  }
#undef STAGE_L

  // ---- stage residual tile Xbf[m0..m0+63][0..255] into XbT (linear) ----
#pragma unroll
  for (int p = 0; p < 8; ++p) {
    const int seg = p * 4 + wv;   // 32 segments x 512 elems (2 rows each)
    gload_lds16(Xbf + (size_t)(m0 + seg * 2 + (ln >> 5)) * 256 +
                    (ln & 31) * 8,
                &XbT[seg * 512]);
  }
  __syncthreads();

  // ---- bias + residual ----
  float gj[4], bj[4], bsj[4];
#pragma unroll
  for (int j = 0; j < 4; ++j) {
    const int n = wv * 64 + j * 16 + fr;
    gj[j] = g[n]; bj[j] = bt[n]; bsj[j] = bias[n];
  }
#pragma unroll
  for (int i = 0; i < 4; ++i) {
#pragma unroll
    for (int r = 0; r < 4; ++r) {
      const int ml = i * 16 + g4 * 4 + r;
#pragma unroll
      for (int j = 0; j < 4; ++j) {
        const int nl = wv * 64 + j * 16 + fr;
        acc[i][j][r] += bsj[j] +
            bu2f(*(const unsigned short*)&XbT[ml * 256 + nl]);
      }
    }
  }
  // ---- LN stats ----
#pragma unroll
  for (int i = 0; i < 4; ++i) {
#pragma unroll
    for (int r = 0; r < 4; ++r) {
      float sp = acc[i][0][r] + acc[i][1][r] + acc[i][2][r] + acc[i][3][r];
      float qp = acc[i][0][r] * acc[i][0][r] + acc[i][1][r] * acc[i][1][r] +
                 acc[i][2][r] * acc[i][2][r] + acc[i][3][r] * acc[i][3][r];
#pragma unroll
      for (int off = 1; off < 16; off <<= 1) {
        sp += __shfl_xor(sp, off);
        qp += __shfl_xor(qp, off);
      }
      if (fr == 0) {
        const int ri = i * 16 + g4 * 4 + r;
        rsum[wv * 64 + ri] = sp;
        rsq[wv * 64 + ri] = qp;
      }
    }
  }
  __syncthreads();
  // ---- normalize + write swizzled bf16 tile ----
#pragma unroll
  for (int i = 0; i < 4; ++i) {
#pragma unroll
    for (int r = 0; r < 4; ++r) {
      const int ri = i * 16 + g4 * 4 + r;
      const float tot = rsum[ri] + rsum[64 + ri] + rsum[128 + ri] +
                        rsum[192 + ri];
      const float tq = rsq[ri] + rsq[64 + ri] + rsq[128 + ri] + rsq[192 + ri];
      const float mu = tot * (1.0f / 256.0f);
      const float var = tq * (1.0f / 256.0f) - mu * mu;
      const float rstd = rsqrtf(var + 1e-5f);
#pragma unroll
      for (int j = 0; j < 4; ++j) {
        const int nl = wv * 64 + j * 16 + fr;
        const float o = (acc[i][j][r] - mu) * rstd * gj[j] + bj[j];
        XbT[ri * 256 + (nl ^ ((ri & 7) << 3))] = __float2bfloat16(o);
      }
    }
  }
  __syncthreads();
#pragma unroll
  for (int p = 0; p < 8; ++p) {
    const int c8 = p * 256 + tid;
    const int row = c8 >> 5, cc = c8 & 31;
    const short8 v =
        *(const short8*)&XbT[row * 256 + ((cc * 8) ^ ((row & 7) << 3))];
    *(short8*)&Xbf[(size_t)(m0 + row) * 256 + cc * 8] = v;
  }
}

// -------- bf16 MFMA flash attention: 512 threads, 8 waves, 128 q-rows ------
// Grid (h fastest, qg, b). Qh/Kh/Ob head-major [b][h][512][32]: all staging
// reads and output writes are fully contiguous (full cache lines).
__global__ __launch_bounds__(512, 8) void attn_mfma_kernel(
    const bf16* __restrict__ Qh, const bf16* __restrict__ Kh,
    const bf16* __restrict__ Vt,
    const int* __restrict__ amask, const int* __restrict__ ntiles,
    const int* __restrict__ ordb, bf16* __restrict__ Ob) {
  const int b = ordb[blockIdx.z];
  const int h = blockIdx.x;          // fastest dim
  const int qg = blockIdx.y;         // 0..3 -> q rows qg*128..+127
  const int tid = threadIdx.x;       // 0..511
  const int wv = tid >> 6, ln = tid & 63;
  const int fr = ln & 15, g4 = ln >> 4;
  const int f8 = (fr & 7) << 3;
  const int rc = (g4 ^ ((fr >> 1) & 3)) * 8;   // swizzled K/Q read chunk
  const size_t bh512 = (size_t)(b * 8 + h) * 512;
  const int bh32 = (b * 8 + h) * 32;
  __shared__ __align__(16) bf16 Ks[2][2048];   // [buf][64][32], chunk-swz
  __shared__ __align__(16) bf16 Vs[2][2048];   // [buf][32 d][64 k] swizzled
  __shared__ __align__(16) bf16 Ps[8192];      // Q staging (128x32); then
                                               // 8 per-wave P tiles [16][64]
  __shared__ __align__(16) float Ms[64];

  const int nt = ntiles[b];

#define STAGE_A(buf, kt_) do {                                                 \
    if (tid < 256) {                                                           \
      const int k0_ = (kt_) * 64;                                              \
      gload_lds16(Kh + (bh512 + k0_ + (tid >> 2)) * 32 + SRC_CHUNK(tid) * 8,   \
                  &Ks[(buf)][wv * 512]);                                       \
      gload_lds16(Vt + (size_t)(bh32 + (tid >> 3)) * 512 + k0_ +               \
                      (tid & 7) * 8,                                           \
                  &Vs[(buf)][wv * 512]);                                       \
      if ((kt_) == nt - 1 && tid < 64)                                         \
        Ms[tid] = (amask[b * S_LEN + k0_ + tid] != 0) ? 0.f : -1e9f;           \
    }                                                                          \
  } while (0)

  // stage 128 Q rows into Ps[0..4095] (wave w -> rows w*16..+15)
  gload_lds16(Qh + (bh512 + qg * 128 + (tid >> 2)) * 32 + SRC_CHUNK(tid) * 8,
              &Ps[wv * 512]);
  STAGE_A(0, 0);
  __syncthreads();
  const short8 qb = *(const short8*)&Ps[wv * 512 + fr * 32 + rc];
  __syncthreads();   // all Q-frag reads done before any P write

  f32x4 accO[2];
  accO[0] = (f32x4){0.f, 0.f, 0.f, 0.f};
  accO[1] = (f32x4){0.f, 0.f, 0.f, 0.f};
  float mrun = -1e30f, lrun = 0.f;   // per-lane state for q = fr (log2 domain)
  const int srcq = 20 * g4;   // shfl src base: lane 16*g4 + (4*g4 + rr)

  int cur = 0;
  for (int kt = 0; kt < nt; ++kt) {
    if (kt + 1 < nt) STAGE_A(cur ^ 1, kt + 1);
    const bool bnd = (kt == nt - 1);

    // S^T = K @ Q^T : 4 MFMAs cover 64 k x 16 q (already log2-scaled via Q)
    f32x4 st[4];
#pragma unroll
    for (int kb = 0; kb < 4; ++kb) {
      const short8 kf = *(const short8*)&Ks[cur][(kb * 16 + fr) * 32 + rc];
      f32x4 z = (f32x4){0.f, 0.f, 0.f, 0.f};
      st[kb] = __builtin_amdgcn_mfma_f32_16x16x32_bf16(kf, qb, z, 0, 0, 0);
    }

    float p[16];
    if (bnd) {
#pragma unroll
      for (int kb = 0; kb < 4; ++kb) {
        const f32x4 mv = ((const f32x4*)Ms)[kb * 4 + g4];
#pragma unroll
        for (int rr = 0; rr < 4; ++rr) p[kb * 4 + rr] = st[kb][rr] + mv[rr];
      }
    } else {
#pragma unroll
      for (int kb = 0; kb < 4; ++kb)
#pragma unroll
        for (int rr = 0; rr < 4; ++rr) p[kb * 4 + rr] = st[kb][rr];
    }

    // max: v_max3 tree (depth 3) + 2 cross-lane
    const float a0 = fmaxf(fmaxf(p[0], p[1]), p[2]);
    const float a1 = fmaxf(fmaxf(p[3], p[4]), p[5]);
    const float a2 = fmaxf(fmaxf(p[6], p[7]), p[8]);
    const float a3 = fmaxf(fmaxf(p[9], p[10]), p[11]);
    const float a4 = fmaxf(fmaxf(p[12], p[13]), p[14]);
    float mx = fmaxf(fmaxf(fmaxf(a0, a1), fmaxf(a2, a3)), fmaxf(a4, p[15]));
    mx = fmaxf(mx, __shfl_xor(mx, 16));
    mx = fmaxf(mx, __shfl_xor(mx, 32));

    // defer-max (T13): rescale only when the row max grew by > 8 (log2)
    float corr = 1.f;
    if (!__all(mx <= mrun + 8.f)) {
      const float mnew = fmaxf(mrun, mx);
      corr = exp2f(mrun - mnew);
      mrun = mnew;
#pragma unroll
      for (int rr = 0; rr < 4; ++rr) {
        const float cs = __shfl(corr, srcq + rr);
        accO[0][rr] *= cs;
        accO[1][rr] *= cs;
      }
    }

#pragma unroll
    for (int i = 0; i < 16; ++i) p[i] = exp2f(p[i] - mrun);
    // pairwise-tree sum (depth 4) + 2 cross-lane
    const float b0 = p[0] + p[1], b1 = p[2] + p[3], b2 = p[4] + p[5],
                b3 = p[6] + p[7], b4 = p[8] + p[9], b5 = p[10] + p[11],
                b6 = p[12] + p[13], b7 = p[14] + p[15];
    float ps = ((b0 + b1) + (b2 + b3)) + ((b4 + b5) + (b6 + b7));
    ps += __shfl_xor(ps, 16);
    ps += __shfl_xor(ps, 32);
    lrun = lrun * corr + ps;

    // write P rows: lane writes 4 shorts per kb at k = kb*16 + g4*4, XOR-swz
#pragma unroll
    for (int kb = 0; kb < 4; ++kb) {
      ushort4 w4;
      w4.x = f2bu(p[kb * 4 + 0]);
      w4.y = f2bu(p[kb * 4 + 1]);
      w4.z = f2bu(p[kb * 4 + 2]);
      w4.w = f2bu(p[kb * 4 + 3]);
      *(ushort4*)&Ps[wv * 1024 + fr * 64 + ((kb * 16 + g4 * 4) ^ f8)] = w4;
    }

    // PV: O[q][d] += P[16q x 32k] @ V[32k x 16d], per-wave (no barrier)
#pragma unroll
    for (int kk = 0; kk < 2; ++kk) {
      const short8 pa = *(const short8*)
          &Ps[wv * 1024 + fr * 64 + ((kk * 32 + g4 * 8) ^ f8)];
#pragma unroll
      for (int df = 0; df < 2; ++df) {
        const short8 vb = *(const short8*)
            &Vs[cur][(df * 16 + fr) * 64 + ((kk * 32 + g4 * 8) ^ f8)];
        accO[df] = __builtin_amdgcn_mfma_f32_16x16x32_bf16(
            pa, vb, accO[df], 0, 0, 0);
      }
    }
    __syncthreads();
    cur ^= 1;
  }
#undef STAGE_A

  const float inv = 1.0f / lrun;   // q = fr layout
#pragma unroll
  for (int rr = 0; rr < 4; ++rr) {
    const float iv = __shfl(inv, srcq + rr);
    const int q = qg * 128 + wv * 16 + g4 * 4 + rr;
    const size_t orow = (bh512 + q) * 32;  // head-major
    Ob[orow + fr]      = __float2bfloat16(accO[0][rr] * iv);
    Ob[orow + 16 + fr] = __float2bfloat16(accO[1][rr] * iv);
  }
}

// -------- fused final-LN + story-pool stage1 (bf16 stream) --------
__global__ __launch_bounds__(256) void lnf_pool_kernel(
    bf16* __restrict__ Xbf, const float* __restrict__ g,
    const float* __restrict__ bt, const int* __restrict__ amask,
    float* __restrict__ Pstory) {
  const int b = blockIdx.x, sg = blockIdx.y;
  const int tid = threadIdx.x, wv = tid >> 6, ln = tid & 63;
  const float4 gg = ((const float4*)g)[ln];
  const float4 bb = ((const float4*)bt)[ln];
  float ax = 0.f, ay = 0.f, az = 0.f, aw = 0.f;
  for (int t = wv; t < 64; t += 4) {
    const size_t tok = (size_t)b * S_LEN + sg * 64 + t;
    const ushort4 u = *(const ushort4*)&Xbf[tok * 256 + ln * 4];
    const float vx = bu2f(u.x), vy = bu2f(u.y), vz = bu2f(u.z),
                vw = bu2f(u.w);
    float s = vx + vy + vz + vw;
#pragma unroll
    for (int off = 1; off < 64; off <<= 1) s += __shfl_xor(s, off);
    const float mu = s * (1.0f / 256.0f);
    const float dx = vx - mu, dy = vy - mu, dz = vz - mu, dw = vw - mu;
    float sq = dx * dx + dy * dy + dz * dz + dw * dw;
#pragma unroll
    for (int off = 1; off < 64; off <<= 1) sq += __shfl_xor(sq, off);
    const float rstd = rsqrtf(sq * (1.0f / 256.0f) + 1e-5f);
    const float ox = dx * rstd * gg.x + bb.x;
    const float oy = dy * rstd * gg.y + bb.y;
    const float oz = dz * rstd * gg.z + bb.z;
    const float ow = dw * rstd * gg.w + bb.w;
    ushort4 o4;
    o4.x = f2bu(ox); o4.y = f2bu(oy); o4.z = f2bu(oz); o4.w = f2bu(ow);
    *(ushort4*)&Xbf[tok * 256 + ln * 4] = o4;
    if (amask[tok]) { ax += ox; ay += oy; az += oz; aw += ow; }
  }
  __shared__ float part[4][256];
  part[wv][ln * 4 + 0] = ax;
  part[wv][ln * 4 + 1] = ay;
  part[wv][ln * 4 + 2] = az;
  part[wv][ln * 4 + 3] = aw;
  __syncthreads();
  const float tot = part[0][tid] + part[1][tid] + part[2][tid] + part[3][tid];
  Pstory[((size_t)b * 8 + sg) * 256 + tid] = tot;
}

// -------- pool combine + classifier: 1024 threads, split k-loop --------
__global__ __launch_bounds__(1024) void poolcls_kernel(
    const bf16* __restrict__ Xbf, const float* __restrict__ Pstory,
    const int* __restrict__ lenb,
    const int* __restrict__ sub_idx, const int* __restrict__ sub_cnt,
    const int* __restrict__ obj_idx, const int* __restrict__ obj_cnt,
    const float* __restrict__ mW1, const float* __restrict__ mb1,
    const float* __restrict__ mW2, const float* __restrict__ mb2,
    float* __restrict__ out) {
  const int b = blockIdx.x, tid = threadIdx.x;
  const int t = tid & 255, sl = tid >> 8;   // channel, slice 0-3
  __shared__ float fs[768];
  __shared__ float part[4][256];
  __shared__ float hid[256];
  __shared__ float w2s[256 * 25];
  const bf16* xb = Xbf + (size_t)b * S_LEN * H_DIM;
  // stage mW2 (25.6KB) while computing fs
  for (int i = tid; i < 6400; i += 1024) w2s[i] = mW2[i];
  if (sl == 0) {
    float s = 0.f;
#pragma unroll
    for (int i = 0; i < 8; ++i) s += Pstory[((size_t)b * 8 + i) * 256 + t];
    fs[512 + t] = s / (float)lenb[b];   // len >= 16
  } else if (sl == 1) {
    const int cc = sub_cnt[b];
    float s2 = 0.f;
    for (int j = 0; j < cc; ++j)
      s2 += __bfloat162float(xb[(size_t)sub_idx[b * 8 + j] * H_DIM + t]);
    fs[t] = (cc > 0) ? s2 / (float)cc : 0.f;
  } else if (sl == 2) {
    const int cc = obj_cnt[b];
    float s2 = 0.f;
    for (int j = 0; j < cc; ++j)
      s2 += __bfloat162float(xb[(size_t)obj_idx[b * 8 + j] * H_DIM + t]);
    fs[256 + t] = (cc > 0) ? s2 / (float)cc : 0.f;
  }
  __syncthreads();
  // hidden GEMM: slice sl covers k in [sl*192, sl*192+192)
  float acc = 0.f;
  for (int k = sl * 192; k < sl * 192 + 192; ++k)
    acc += fs[k] * mW1[(size_t)k * 256 + t];
  part[sl][t] = acc;
  __syncthreads();
  if (sl == 0)
    hid[t] = fmaxf(part[0][t] + part[1][t] + part[2][t] + part[3][t] +
                       mb1[t],
                   0.f);
  __syncthreads();
  if (tid < 25) {
    float o = mb2[tid];
    for (int j = 0; j < 256; ++j) o += hid[j] * w2s[j * 25 + tid];
    out[b * 25 + tid] = o;
  }
}

// ---------------------------------------------------------------------------
extern "C" void kernel_launch(void* const* d_in, const int* in_sizes, int n_in,
                              void* d_out, int out_size, void* d_ws, size_t ws_size,
                              hipStream_t stream) {
  const int*   input_ids = (const int*)d_in[0];
  const int*   amask     = (const int*)d_in[1];
  const int*   sub_idx   = (const int*)d_in[2];
  const int*   sub_cnt   = (const int*)d_in[3];
  const int*   obj_idx   = (const int*)d_in[4];
  const int*   obj_cnt   = (const int*)d_in[5];
  const float* emb  = (const float*)d_in[6];
  const float* Wqkv = (const float*)d_in[7];
  const float* bqkv = (const float*)d_in[8];
  const float* Wo   = (const float*)d_in[9];
  const float* bo   = (const float*)d_in[10];
  const float* ln1g = (const float*)d_in[11];
  const float* ln1b = (const float*)d_in[12];
  const float* ln2g = (const float*)d_in[13];
  const float* ln2b = (const float*)d_in[14];
  const float* W1   = (const float*)d_in[15];
  const float* b1   = (const float*)d_in[16];
  const float* W2   = (const float*)d_in[17];
  const float* b2   = (const float*)d_in[18];
  const float* lnfg = (const float*)d_in[19];
  const float* lnfb = (const float*)d_in[20];
  const float* mW1  = (const float*)d_in[21];
  const float* mb1  = (const float*)d_in[22];
  const float* mW2  = (const float*)d_in[23];
  const float* mb2  = (const float*)d_in[24];
  float* out = (float*)d_out;

  // workspace layout (bytes)
  char* w = (char*)d_ws;
  bf16*  Xb   = (bf16*)w;                          w += (size_t)NTOK * 256 * 2;  // 16.8MB
  bf16*  Qh   = (bf16*)w;                          w += (size_t)NTOK * 256 * 2;  // 16.8MB
  bf16*  Kh   = (bf16*)w;                          w += (size_t)NTOK * 256 * 2;  // 16.8MB
  bf16*  Vtg  = (bf16*)w;                          w += (size_t)NTOK * 256 * 2;  // 16.8MB
  bf16*  Ob   = (bf16*)w;                          w += (size_t)NTOK * 256 * 2;  // 16.8MB
  bf16*  Wqkvt= (bf16*)w;                          w += (size_t)4 * 768 * 256 * 2;
  bf16*  Wot  = (bf16*)w;                          w += (size_t)4 * 256 * 256 * 2;
  bf16*  W1t  = (bf16*)w;                          w += (size_t)4 * 1024 * 256 * 2;
  bf16*  W2t  = (bf16*)w;                          w += (size_t)4 * 256 * 1024 * 2;
  float* Pstory = (float*)w;                       w += (size_t)64 * 8 * 256 * 4;
  int*   ntiles = (int*)w;                         w += 256;
  int*   lenb   = (int*)w;                         w += 256;
  int*   ordb   = (int*)w;                         w += 256;
  bf16*  Hb   = Qh;   // aliases [Qh,Kh,Vtg,Ob] = 67.1MB = 32768*1024*2

  lens_kernel<<<64, 64, 0, stream>>>(amask, ntiles, lenb);
  order_kernel<<<1, 64, 0, stream>>>(ntiles, ordb);
  tcast_kernel<<<dim3(24, 8, 4), 256, 0, stream>>>(Wqkv, Wqkvt, 256, 768);
  tcast_kernel<<<dim3(8, 8, 4), 256, 0, stream>>>(Wo, Wot, 256, 256);
  tcast_kernel<<<dim3(32, 8, 4), 256, 0, stream>>>(W1, W1t, 256, 1024);
  tcast_kernel<<<dim3(8, 32, 4), 256, 0, stream>>>(W2, W2t, 1024, 256);

  embed_kernel<<<8192, 256, 0, stream>>>(input_ids, emb, Xb);

  for (int l = 0; l < 4; ++l) {
    const bf16* Wqkvt_l = Wqkvt + (size_t)l * 768 * 256;
    const bf16* Wot_l   = Wot + (size_t)l * 256 * 256;
    const bf16* W1t_l   = W1t + (size_t)l * 1024 * 256;
    const bf16* W2t_l   = W2t + (size_t)l * 256 * 1024;

    hgemm_kernel<2, false><<<dim3(256, 6), 256, 0, stream>>>(
        Xb, Wqkvt_l, bqkv + (size_t)l * 768, Qh, Kh, Vtg, NTOK, 768, 256);
    attn_mfma_kernel<<<dim3(8, 4, 64), 512, 0, stream>>>(
        Qh, Kh, Vtg, amask, ntiles, ordb, Ob);
    hgemm_ln_kernel<true><<<512, 256, 0, stream>>>(
        Ob, Wot_l, bo + (size_t)l * 256, Xb,
        ln1g + l * 256, ln1b + l * 256, 256);
    hgemm_kernel<1, true><<<dim3(256, 8), 256, 0, stream>>>(
        Xb, W1t_l, b1 + (size_t)l * 1024, Hb, nullptr, nullptr,
        NTOK, 1024, 256);
    hgemm_ln_kernel<false><<<512, 256, 0, stream>>>(
        Hb, W2t_l, b2 + (size_t)l * 256, Xb,
        ln2g + l * 256, ln2b + l * 256, 1024);
  }
  lnf_pool_kernel<<<dim3(64, 8), 256, 0, stream>>>(Xb, lnfg, lnfb, amask,
                                                   Pstory);
  poolcls_kernel<<<64, 1024, 0, stream>>>(Xb, Pstory, lenb, sub_idx, sub_cnt,
                                          obj_idx, obj_cnt, mW1, mb1, mW2, mb2,
                                          out);
}